// Round 2
// baseline (16387.985 us; speedup 1.0000x reference)
//
#include <hip/hip_runtime.h>
#include <stdint.h>

typedef short  s8v  __attribute__((ext_vector_type(8)));
typedef float  f4v  __attribute__((ext_vector_type(4)));
typedef float  f2v  __attribute__((ext_vector_type(2)));
typedef int    i4v  __attribute__((ext_vector_type(4)));
typedef unsigned short us4 __attribute__((ext_vector_type(4)));

#define MFMA16(a,b,c) __builtin_amdgcn_mfma_f32_16x16x32_bf16(a,b,c,0,0,0)

#define K1 1.44269504088896340f   /* log2(e)   */
#define K2 2.88539008177792681f   /* 2*log2(e) */

__device__ __forceinline__ unsigned short f2bf(float f) {
  union { float f; uint32_t u; } v; v.f = f;
  return (unsigned short)((v.u + 0x7FFFu + ((v.u >> 16) & 1u)) >> 16);
}
__device__ __forceinline__ float bflo(uint32_t dw) {
  union { uint32_t u; float f; } v; v.u = dw << 16; return v.f;
}
__device__ __forceinline__ float bfhi(uint32_t dw) {
  union { uint32_t u; float f; } v; v.u = dw & 0xFFFF0000u; return v.f;
}
__device__ __forceinline__ float bfu(unsigned short u) {
  union { uint32_t u; float f; } v; v.u = ((uint32_t)u) << 16; return v.f;
}

// ---------------- prep: convert weights to bf16, sum biases ----------------
__global__ __launch_bounds__(256) void prep_kernel(
    const float* __restrict__ We, const float* __restrict__ Ue,
    const float* __restrict__ Wih, const float* __restrict__ Whh,
    const float* __restrict__ bih, const float* __restrict__ bhh,
    unsigned short* __restrict__ Wih_b, unsigned short* __restrict__ Whh_b,
    unsigned short* __restrict__ We_b, unsigned short* __restrict__ Ue_b,
    float* __restrict__ bsum)
{
  int i0 = blockIdx.x * 256 + threadIdx.x;
  int stride = gridDim.x * 256;
  for (int i = i0; i < 262144; i += stride) Wih_b[i] = f2bf(Wih[i]);
  for (int i = i0; i < 262144; i += stride) Whh_b[i] = f2bf(Whh[i]);
  for (int i = i0; i < 65536;  i += stride) We_b[i]  = f2bf(We[i]);
  for (int i = i0; i < 16384;  i += stride) Ue_b[i]  = f2bf(Ue[i]);
  for (int i = i0; i < 1024;   i += stride) bsum[i]  = bih[i] + bhh[i];
}

// ---- Ux GEMM: UxK8[b][tg][n][16] = fp8(K2 * sum_t x[b][t][n]*U_e[s][t]) ----
// layout: b*2048 + tg*256 + n  (16-byte units, 16 t per chunk)
__global__ __launch_bounds__(256) void ux_kernel(
    const float* __restrict__ x, const unsigned short* __restrict__ Ue_b,
    unsigned char* __restrict__ UxK8)
{
  __shared__ unsigned short xT[64 * 136];  // x[b][t][n] -> [n][t], padded
  __shared__ unsigned short oT[64 * 136];  // result rows n, cols s (bf16)
  const int tid = threadIdx.x;
  const int b   = blockIdx.x >> 2;
  const int n0  = (blockIdx.x & 3) * 64;

  {
    const int nl = tid & 63, tp = tid >> 6;
    for (int i = 0; i < 32; i++) {
      int t = tp + i * 4;
      xT[nl * 136 + t] = f2bf(x[((size_t)b * 128 + t) * 256 + n0 + nl]);
    }
  }
  __syncthreads();
  {
    const int w = tid >> 6, lane = tid & 63;
    const int l15 = lane & 15, quad = lane >> 4;
    for (int tt = 0; tt < 8; tt++) {
      f4v acc = {0.f, 0.f, 0.f, 0.f};
      #pragma unroll
      for (int kt = 0; kt < 4; kt++) {
        s8v a  = *(const s8v*)&xT[(w * 16 + l15) * 136 + kt * 32 + quad * 8];
        s8v bb = *(const s8v*)&Ue_b[(tt * 16 + l15) * 128 + kt * 32 + quad * 8];
        acc = MFMA16(a, bb, acc);
      }
      #pragma unroll
      for (int r = 0; r < 4; r++)
        oT[(w * 16 + quad * 4 + r) * 136 + tt * 16 + l15] = f2bf(acc[r] * K2);
    }
  }
  __syncthreads();
  {
    for (int p = 0; p < 2; p++) {
      int row = (tid >> 3) + p * 32;   // local n
      int tg  = tid & 7;               // 16-t chunk
      const unsigned int* sp = (const unsigned int*)&oT[row * 136 + tg * 16];
      i4v outv;
      #pragma unroll
      for (int j = 0; j < 4; j++) {
        unsigned int d0 = sp[2 * j], d1 = sp[2 * j + 1];
        int w = __builtin_amdgcn_cvt_pk_fp8_f32(bflo(d0), bfhi(d0), 0, 0);
        w     = __builtin_amdgcn_cvt_pk_fp8_f32(bflo(d1), bfhi(d1), w, 1);
        outv[j] = w;
      }
      *(i4v*)&UxK8[(((size_t)b * 8 + tg) * 256 + n0 + row) * 16] = outv;
    }
  }
}

// ---------------- persistent recurrence: 256 blocks x 1024 thr, 8 batch/blk --
__global__ __launch_bounds__(1024, 4) void rnn_kernel(
    const unsigned char* __restrict__ UxK8,
    const unsigned short* __restrict__ We_b,
    const unsigned short* __restrict__ Wih_b,
    const unsigned short* __restrict__ Whh_b,
    const float* __restrict__ bsum_g,
    const float* __restrict__ Ve,
    float* __restrict__ out)
{
  __shared__ unsigned short h_hist[2048 * 20];  // 80 KB: bf16 h, depth 16, stride 20
  __shared__ unsigned short xt_b[16 * 264];     // bf16, rows 8..15 zero-pad
  __shared__ unsigned short h_b [16 * 264];
  __shared__ unsigned short c_b [16 * 264];
  __shared__ float  c_f[8 * 256];               // f32 cell state
  __shared__ float  e_f[8 * 256];
  __shared__ float  wv_lds[8 * 128 * 2];        // [b][t] -> (K2*whs, -2*V)
  __shared__ float  bsum[1024];
  __shared__ float  Zpart[8][4];

  const int tid  = threadIdx.x;
  const int wv   = tid >> 6;
  const int lane = tid & 63;
  const int l15  = lane & 15;
  const int quad = lane >> 4;
  const int blk  = blockIdx.x;

  for (int i = tid; i < 16 * 264; i += 1024) { xt_b[i] = 0; h_b[i] = 0; c_b[i] = 0; }
  for (int i = tid; i < 2048; i += 1024) c_f[i] = 0.f;
  bsum[tid] = bsum_g[tid];
  {
    int b8 = tid >> 7, t = tid & 127;
    wv_lds[(b8 * 128 + t) * 2 + 1] = -2.0f * Ve[t];
    wv_lds[(b8 * 128 + t) * 2 + 0] = 0.f;
  }
  float Vs = 0.f;
  for (int t = 0; t < 128; t++) Vs += Ve[t];
  __syncthreads();

  const int an = tid & 255;   // n index owned by this thread
  const int bq = tid >> 8;    // handles batches bq and bq+4

  const i4v* ub = (const i4v*)UxK8;
  const size_t ux_base0 = ((size_t)(blk * 8 + bq)    ) * 2048 + an;
  const size_t ux_base1 = ((size_t)(blk * 8 + bq + 4)) * 2048 + an;

  // UxK8 is loop-invariant: hold this thread's 2x128B fp8 slice in VGPRs
  // for the whole recurrence. Removes 8.6 GB of per-step L2-miss traffic
  // AND the L2 streaming thrash that was evicting the gate weights every
  // step (FETCH showed 170 MB/step vs ~76 MB unique). 64 VGPRs; the
  // 1024-thread block caps us at 128 VGPRs (4 waves/SIMD) so this fits
  // without an occupancy change — gate loads de-paired below to keep the
  // transient pressure under the cap.
  i4v ux0[8], ux1[8];
  #pragma unroll
  for (int tg = 0; tg < 8; tg++) {
    ux0[tg] = ub[ux_base0 + (size_t)tg * 256];
    ux1[tg] = ub[ux_base1 + (size_t)tg * 256];
  }

  f4v ga0, ga1, ga2, ga3;

  for (int s = 0; s < 128; s++) {
    __syncthreads();   // B1: h_b/c_b stable from previous step

    // ---- whs = [h,c] @ W_e.T  (waves 0..7, t-tile = wv) ----
    if (wv < 8) {
      f4v acc = {0.f, 0.f, 0.f, 0.f};
      #pragma unroll
      for (int kt = 0; kt < 8; kt++) {
        s8v a  = *(const s8v*)&h_b[l15 * 264 + kt * 32 + quad * 8];
        s8v bb = *(const s8v*)&We_b[(wv * 16 + l15) * 512 + kt * 32 + quad * 8];
        acc = MFMA16(a, bb, acc);
      }
      #pragma unroll
      for (int kt = 0; kt < 8; kt++) {
        s8v a  = *(const s8v*)&c_b[l15 * 264 + kt * 32 + quad * 8];
        s8v bb = *(const s8v*)&We_b[(wv * 16 + l15) * 512 + 256 + kt * 32 + quad * 8];
        acc = MFMA16(a, bb, acc);
      }
      if (lane < 32) {
        #pragma unroll
        for (int r = 0; r < 4; r++)
          wv_lds[((quad * 4 + r) * 128 + wv * 16 + l15) * 2] = K2 * acc[r];
      }
    }
    __syncthreads();   // B2: whsK ready

    // ---- h-part of gates (all 16 waves), single-kt to bound VGPR pressure ----
    ga0 = (f4v){0.f,0.f,0.f,0.f}; ga1 = ga0; ga2 = ga0; ga3 = ga0;
    #pragma unroll
    for (int kt = 0; kt < 8; kt++) {
      s8v aA = *(const s8v*)&h_b[l15 * 264 + kt * 32 + quad * 8];
      const int r0 = (wv * 16 + l15) * 256;
      s8v b0 = *(const s8v*)&Whh_b[(size_t)(     0 + r0) + kt * 32 + quad * 8];
      s8v b1 = *(const s8v*)&Whh_b[(size_t)( 65536 + r0) + kt * 32 + quad * 8];
      s8v b2 = *(const s8v*)&Whh_b[(size_t)(131072 + r0) + kt * 32 + quad * 8];
      s8v b3 = *(const s8v*)&Whh_b[(size_t)(196608 + r0) + kt * 32 + quad * 8];
      ga0 = MFMA16(aA, b0, ga0); ga1 = MFMA16(aA, b1, ga1);
      ga2 = MFMA16(aA, b2, ga2); ga3 = MFMA16(aA, b3, ga3);
    }

    // ---- attention: e[b][n] = Vs + sum_t (-2 V[t]) / (exp2(UxK+whsK)+1) ----
    // UxK values come from the register-resident slice — no global loads here.
    #pragma unroll
    for (int pass = 0; pass < 2; pass++) {
      const int bb8 = bq + pass * 4;
      const f4v* wvf = (const f4v*)&wv_lds[bb8 * 256];
      float a0 = 0.f, a1 = 0.f, a2 = 0.f, a3 = 0.f;
      #pragma unroll
      for (int tg = 0; tg < 8; tg++) {
        i4v cur = pass ? ux1[tg] : ux0[tg];
        #pragma unroll
        for (int q = 0; q < 4; q++) {
          uint32_t dw = (uint32_t)cur[q];
          f2v lo = __builtin_amdgcn_cvt_pk_f32_fp8(dw, 0);
          f2v hi = __builtin_amdgcn_cvt_pk_f32_fp8(dw, 1);
          const int t = tg * 16 + q * 4;
          f4v w01 = wvf[(t >> 1)];       // (whs_t, -2V_t, whs_t+1, -2V_t+1)
          f4v w23 = wvf[(t >> 1) + 1];
          float x0 = lo.x + w01.x;
          a0 = fmaf(w01.y, __builtin_amdgcn_rcpf(__builtin_amdgcn_exp2f(x0) + 1.0f), a0);
          float x1 = lo.y + w01.z;
          a1 = fmaf(w01.w, __builtin_amdgcn_rcpf(__builtin_amdgcn_exp2f(x1) + 1.0f), a1);
          float x2 = hi.x + w23.x;
          a2 = fmaf(w23.y, __builtin_amdgcn_rcpf(__builtin_amdgcn_exp2f(x2) + 1.0f), a2);
          float x3 = hi.y + w23.z;
          a3 = fmaf(w23.w, __builtin_amdgcn_rcpf(__builtin_amdgcn_exp2f(x3) + 1.0f), a3);
        }
      }
      float e = Vs + ((a0 + a1) + (a2 + a3));
      e_f[bb8 * 256 + an] = e;
      float pe = __builtin_amdgcn_exp2f(K1 * e);
      #pragma unroll
      for (int off = 32; off >= 1; off >>= 1) pe += __shfl_xor(pe, off);
      if (lane == 0) Zpart[bb8][wv & 3] = pe;
    }
    __syncthreads();  // B3: e_f + Zpart ready

    // ---- softmax redistribution + xt (bf16) ----
    {
      const int b8s = tid >> 7;
      const int nn0 = (tid & 127) * 2;
      f4v zp = *(const f4v*)&Zpart[b8s][0];
      float zi = 1.0f / ((zp.x + zp.y) + (zp.z + zp.w));
      float2 ee = *(const float2*)&e_f[b8s * 256 + nn0];
      float p0 = __builtin_amdgcn_exp2f(K1 * ee.x);
      float p1 = __builtin_amdgcn_exp2f(K1 * ee.y);
      unsigned int packed = (unsigned int)f2bf(p0 * zi * ee.x)
                          | ((unsigned int)f2bf(p1 * zi * ee.y) << 16);
      *(unsigned int*)&xt_b[b8s * 264 + nn0] = packed;
    }
    __syncthreads();  // B4: xt ready

    // ---- xt-part of gates ----
    #pragma unroll
    for (int kt = 0; kt < 8; kt++) {
      s8v aA = *(const s8v*)&xt_b[l15 * 264 + kt * 32 + quad * 8];
      const int r0 = (wv * 16 + l15) * 256;
      s8v b0 = *(const s8v*)&Wih_b[(size_t)(     0 + r0) + kt * 32 + quad * 8];
      s8v b1 = *(const s8v*)&Wih_b[(size_t)( 65536 + r0) + kt * 32 + quad * 8];
      s8v b2 = *(const s8v*)&Wih_b[(size_t)(131072 + r0) + kt * 32 + quad * 8];
      s8v b3 = *(const s8v*)&Wih_b[(size_t)(196608 + r0) + kt * 32 + quad * 8];
      ga0 = MFMA16(aA, b0, ga0); ga1 = MFMA16(aA, b1, ga1);
      ga2 = MFMA16(aA, b2, ga2); ga3 = MFMA16(aA, b3, ga3);
    }

    // ---- pointwise LSTM straight from accumulators (lanes 0..31) ----
    if (lane < 32) {
      const int jj = wv * 16 + l15;
      #pragma unroll
      for (int r = 0; r < 4; r++) {
        const int m = quad * 4 + r;
        float iG = ga0[r] + bsum[jj];
        float fG = ga1[r] + bsum[256 + jj];
        float gG = ga2[r] + bsum[512 + jj];
        float oG = ga3[r] + bsum[768 + jj];
        float si = __builtin_amdgcn_rcpf(1.0f + __builtin_amdgcn_exp2f(-K1 * iG));
        float sf = __builtin_amdgcn_rcpf(1.0f + __builtin_amdgcn_exp2f(-K1 * fG));
        float so = __builtin_amdgcn_rcpf(1.0f + __builtin_amdgcn_exp2f(-K1 * oG));
        float tg_ = 1.0f - 2.0f * __builtin_amdgcn_rcpf(1.0f + __builtin_amdgcn_exp2f(K2 * gG));
        float cn = sf * c_f[m * 256 + jj] + si * tg_;
        float th = 1.0f - 2.0f * __builtin_amdgcn_rcpf(1.0f + __builtin_amdgcn_exp2f(K2 * cn));
        float hn = so * th;
        c_f[m * 256 + jj] = cn;
        c_b[m * 264 + jj] = f2bf(cn);
        h_b[m * 264 + jj] = f2bf(hn);
        h_hist[(m * 256 + jj) * 20 + (s & 15)] = f2bf(hn);
      }
    }

    // ---- full-line coalesced output dump every 16 steps (plain stores:
    //      L2 write-back merges the 4x16B into whole 64B lines, no RMW) ----
    if ((s & 15) == 15) {
      __syncthreads();
      #pragma unroll
      for (int p = 0; p < 2; p++) {
        int rid = p * 1024 + tid;
        int mB = rid >> 8, j = rid & 255;
        const us4* hp = (const us4*)&h_hist[rid * 20];
        float* dst = &out[(((size_t)blk * 8 + mB) * 256 + j) * 128 + (s - 15)];
        #pragma unroll
        for (int c = 0; c < 4; c++) {
          us4 u = hp[c];
          f4v o = { bfu(u.x), bfu(u.y), bfu(u.z), bfu(u.w) };
          *(f4v*)(dst + c * 4) = o;
        }
      }
    }
  }
}

extern "C" void kernel_launch(void* const* d_in, const int* in_sizes, int n_in,
                              void* d_out, int out_size, void* d_ws, size_t ws_size,
                              hipStream_t stream) {
  const float* x   = (const float*)d_in[0];
  const float* We  = (const float*)d_in[1];
  const float* Ue  = (const float*)d_in[2];
  const float* Ve  = (const float*)d_in[3];
  const float* Wih = (const float*)d_in[4];
  const float* Whh = (const float*)d_in[5];
  const float* bih = (const float*)d_in[6];
  const float* bhh = (const float*)d_in[7];
  float* out = (float*)d_out;

  char* p = (char*)d_ws;
  unsigned char*  UxK8  = (unsigned char*)p;  p += (size_t)67108864; // 2048*256*128 fp8
  unsigned short* Wih_b = (unsigned short*)p; p += 524288;
  unsigned short* Whh_b = (unsigned short*)p; p += 524288;
  unsigned short* We_b  = (unsigned short*)p; p += 131072;
  unsigned short* Ue_b  = (unsigned short*)p; p += 32768;
  float* bsum = (float*)p;

  prep_kernel<<<512, 256, 0, stream>>>(We, Ue, Wih, Whh, bih, bhh,
                                       Wih_b, Whh_b, We_b, Ue_b, bsum);
  ux_kernel<<<8192, 256, 0, stream>>>(x, Ue_b, UxK8);
  rnn_kernel<<<256, 1024, 0, stream>>>(UxK8, We_b, Wih_b, Whh_b, bsum, Ve, out);
}

// Round 3
// 15777.771 us; speedup vs baseline: 1.0387x; 1.0387x over previous
//
#include <hip/hip_runtime.h>
#include <stdint.h>

typedef short  s8v  __attribute__((ext_vector_type(8)));
typedef float  f4v  __attribute__((ext_vector_type(4)));
typedef float  f2v  __attribute__((ext_vector_type(2)));
typedef int    i4v  __attribute__((ext_vector_type(4)));
typedef unsigned short us4 __attribute__((ext_vector_type(4)));

#define MFMA16(a,b,c) __builtin_amdgcn_mfma_f32_16x16x32_bf16(a,b,c,0,0,0)

#define K1 1.44269504088896340f   /* log2(e)   */
#define K2 2.88539008177792681f   /* 2*log2(e) */

__device__ __forceinline__ unsigned short f2bf(float f) {
  union { float f; uint32_t u; } v; v.f = f;
  return (unsigned short)((v.u + 0x7FFFu + ((v.u >> 16) & 1u)) >> 16);
}
__device__ __forceinline__ float bflo(uint32_t dw) {
  union { uint32_t u; float f; } v; v.u = dw << 16; return v.f;
}
__device__ __forceinline__ float bfhi(uint32_t dw) {
  union { uint32_t u; float f; } v; v.u = dw & 0xFFFF0000u; return v.f;
}
__device__ __forceinline__ float bfu(unsigned short u) {
  union { uint32_t u; float f; } v; v.u = ((uint32_t)u) << 16; return v.f;
}

// one 16-t chunk of the attention sum; tg must be a compile-time constant at
// every call site so the wv_lds indices stay static.
__device__ __forceinline__ void att_accum(i4v cur, const f4v* __restrict__ wvf, int tg,
                                          float& a0, float& a1, float& a2, float& a3) {
  #pragma unroll
  for (int q = 0; q < 4; q++) {
    uint32_t dw = (uint32_t)cur[q];
    f2v lo = __builtin_amdgcn_cvt_pk_f32_fp8(dw, 0);
    f2v hi = __builtin_amdgcn_cvt_pk_f32_fp8(dw, 1);
    const int t = tg * 16 + q * 4;
    f4v w01 = wvf[(t >> 1)];       // (whs_t, -2V_t, whs_t+1, -2V_t+1)
    f4v w23 = wvf[(t >> 1) + 1];
    float x0 = lo.x + w01.x;
    a0 = fmaf(w01.y, __builtin_amdgcn_rcpf(__builtin_amdgcn_exp2f(x0) + 1.0f), a0);
    float x1 = lo.y + w01.z;
    a1 = fmaf(w01.w, __builtin_amdgcn_rcpf(__builtin_amdgcn_exp2f(x1) + 1.0f), a1);
    float x2 = hi.x + w23.x;
    a2 = fmaf(w23.y, __builtin_amdgcn_rcpf(__builtin_amdgcn_exp2f(x2) + 1.0f), a2);
    float x3 = hi.y + w23.z;
    a3 = fmaf(w23.w, __builtin_amdgcn_rcpf(__builtin_amdgcn_exp2f(x3) + 1.0f), a3);
  }
}

// ---------------- prep: convert weights to bf16, sum biases ----------------
__global__ __launch_bounds__(256) void prep_kernel(
    const float* __restrict__ We, const float* __restrict__ Ue,
    const float* __restrict__ Wih, const float* __restrict__ Whh,
    const float* __restrict__ bih, const float* __restrict__ bhh,
    unsigned short* __restrict__ Wih_b, unsigned short* __restrict__ Whh_b,
    unsigned short* __restrict__ We_b, unsigned short* __restrict__ Ue_b,
    float* __restrict__ bsum)
{
  int i0 = blockIdx.x * 256 + threadIdx.x;
  int stride = gridDim.x * 256;
  for (int i = i0; i < 262144; i += stride) Wih_b[i] = f2bf(Wih[i]);
  for (int i = i0; i < 262144; i += stride) Whh_b[i] = f2bf(Whh[i]);
  for (int i = i0; i < 65536;  i += stride) We_b[i]  = f2bf(We[i]);
  for (int i = i0; i < 16384;  i += stride) Ue_b[i]  = f2bf(Ue[i]);
  for (int i = i0; i < 1024;   i += stride) bsum[i]  = bih[i] + bhh[i];
}

// ---- Ux GEMM: UxK8[b][tg][n][16] = fp8(K2 * sum_t x[b][t][n]*U_e[s][t]) ----
// layout: b*2048 + tg*256 + n  (16-byte units, 16 t per chunk)
__global__ __launch_bounds__(256) void ux_kernel(
    const float* __restrict__ x, const unsigned short* __restrict__ Ue_b,
    unsigned char* __restrict__ UxK8)
{
  __shared__ unsigned short xT[64 * 136];  // x[b][t][n] -> [n][t], padded
  __shared__ unsigned short oT[64 * 136];  // result rows n, cols s (bf16)
  const int tid = threadIdx.x;
  const int b   = blockIdx.x >> 2;
  const int n0  = (blockIdx.x & 3) * 64;

  {
    const int nl = tid & 63, tp = tid >> 6;
    for (int i = 0; i < 32; i++) {
      int t = tp + i * 4;
      xT[nl * 136 + t] = f2bf(x[((size_t)b * 128 + t) * 256 + n0 + nl]);
    }
  }
  __syncthreads();
  {
    const int w = tid >> 6, lane = tid & 63;
    const int l15 = lane & 15, quad = lane >> 4;
    for (int tt = 0; tt < 8; tt++) {
      f4v acc = {0.f, 0.f, 0.f, 0.f};
      #pragma unroll
      for (int kt = 0; kt < 4; kt++) {
        s8v a  = *(const s8v*)&xT[(w * 16 + l15) * 136 + kt * 32 + quad * 8];
        s8v bb = *(const s8v*)&Ue_b[(tt * 16 + l15) * 128 + kt * 32 + quad * 8];
        acc = MFMA16(a, bb, acc);
      }
      #pragma unroll
      for (int r = 0; r < 4; r++)
        oT[(w * 16 + quad * 4 + r) * 136 + tt * 16 + l15] = f2bf(acc[r] * K2);
    }
  }
  __syncthreads();
  {
    for (int p = 0; p < 2; p++) {
      int row = (tid >> 3) + p * 32;   // local n
      int tg  = tid & 7;               // 16-t chunk
      const unsigned int* sp = (const unsigned int*)&oT[row * 136 + tg * 16];
      i4v outv;
      #pragma unroll
      for (int j = 0; j < 4; j++) {
        unsigned int d0 = sp[2 * j], d1 = sp[2 * j + 1];
        int w = __builtin_amdgcn_cvt_pk_fp8_f32(bflo(d0), bfhi(d0), 0, 0);
        w     = __builtin_amdgcn_cvt_pk_fp8_f32(bflo(d1), bfhi(d1), w, 1);
        outv[j] = w;
      }
      *(i4v*)&UxK8[(((size_t)b * 8 + tg) * 256 + n0 + row) * 16] = outv;
    }
  }
}

// ---------------- persistent recurrence: 256 blocks x 1024 thr, 8 batch/blk --
__global__ __launch_bounds__(1024, 4) void rnn_kernel(
    const unsigned char* __restrict__ UxK8,
    const unsigned short* __restrict__ We_b,
    const unsigned short* __restrict__ Wih_b,
    const unsigned short* __restrict__ Whh_b,
    const float* __restrict__ bsum_g,
    const float* __restrict__ Ve,
    float* __restrict__ out)
{
  __shared__ unsigned short h_hist[2048 * 20];  // 80 KB: bf16 h, depth 16, stride 20
  __shared__ unsigned short xt_b[16 * 264];     // bf16, rows 8..15 zero-pad
  __shared__ unsigned short h_b [16 * 264];
  __shared__ unsigned short c_b [16 * 264];
  __shared__ float  c_f[8 * 256];               // f32 cell state
  __shared__ float  e_f[8 * 256];
  __shared__ float  wv_lds[8 * 128 * 2];        // [b][t] -> (K2*whs, -2*V)
  __shared__ float  bsum[1024];
  __shared__ float  Zpart[8][4];

  const int tid  = threadIdx.x;
  const int wv   = tid >> 6;
  const int lane = tid & 63;
  const int l15  = lane & 15;
  const int quad = lane >> 4;
  const int blk  = blockIdx.x;

  for (int i = tid; i < 16 * 264; i += 1024) { xt_b[i] = 0; h_b[i] = 0; c_b[i] = 0; }
  for (int i = tid; i < 2048; i += 1024) c_f[i] = 0.f;
  bsum[tid] = bsum_g[tid];
  {
    int b8 = tid >> 7, t = tid & 127;
    wv_lds[(b8 * 128 + t) * 2 + 1] = -2.0f * Ve[t];
    wv_lds[(b8 * 128 + t) * 2 + 0] = 0.f;
  }
  float Vs = 0.f;
  for (int t = 0; t < 128; t++) Vs += Ve[t];
  __syncthreads();

  const int an = tid & 255;   // n index owned by this thread
  const int bq = tid >> 8;    // handles batches bq and bq+4

  const i4v* ub = (const i4v*)UxK8;
  const size_t ux_base0 = ((size_t)(blk * 8 + bq)    ) * 2048 + an;
  const size_t ux_base1 = ((size_t)(blk * 8 + bq + 4)) * 2048 + an;

  // Batch bq's loop-invariant UxK8 slice lives in 8 NAMED i4v registers
  // (32 VGPRs). Round-2 lesson: a 64-VGPR array under the hard 128-VGPR
  // cap (1024 thr, 4 waves/SIMD) spilled to scratch and ADDED 8 GB of
  // fetch. 32 persistent + ~60 transient fits. Batch bq+4 is streamed
  // with NONTEMPORAL loads so the stream can't evict the L2-resident
  // gate weights (the round-0 thrash: 8 MB/XCD/step through 4 MB L2).
  i4v u0 = ub[ux_base0];
  i4v u1 = ub[ux_base0 + 256];
  i4v u2 = ub[ux_base0 + 512];
  i4v u3 = ub[ux_base0 + 768];
  i4v u4 = ub[ux_base0 + 1024];
  i4v u5 = ub[ux_base0 + 1280];
  i4v u6 = ub[ux_base0 + 1536];
  i4v u7 = ub[ux_base0 + 1792];

  f4v ga0, ga1, ga2, ga3;

  for (int s = 0; s < 128; s++) {
    __syncthreads();   // B1: h_b/c_b stable from previous step

    // ---- whs = [h,c] @ W_e.T  (waves 0..7, t-tile = wv) ----
    if (wv < 8) {
      f4v acc = {0.f, 0.f, 0.f, 0.f};
      #pragma unroll
      for (int kt = 0; kt < 8; kt++) {
        s8v a  = *(const s8v*)&h_b[l15 * 264 + kt * 32 + quad * 8];
        s8v bb = *(const s8v*)&We_b[(wv * 16 + l15) * 512 + kt * 32 + quad * 8];
        acc = MFMA16(a, bb, acc);
      }
      #pragma unroll
      for (int kt = 0; kt < 8; kt++) {
        s8v a  = *(const s8v*)&c_b[l15 * 264 + kt * 32 + quad * 8];
        s8v bb = *(const s8v*)&We_b[(wv * 16 + l15) * 512 + 256 + kt * 32 + quad * 8];
        acc = MFMA16(a, bb, acc);
      }
      if (lane < 32) {
        #pragma unroll
        for (int r = 0; r < 4; r++)
          wv_lds[((quad * 4 + r) * 128 + wv * 16 + l15) * 2] = K2 * acc[r];
      }
    }
    __syncthreads();   // B2: whsK ready

    // ---- h-part of gates (all 16 waves), single-kt to bound VGPR pressure ----
    ga0 = (f4v){0.f,0.f,0.f,0.f}; ga1 = ga0; ga2 = ga0; ga3 = ga0;
    #pragma unroll
    for (int kt = 0; kt < 8; kt++) {
      s8v aA = *(const s8v*)&h_b[l15 * 264 + kt * 32 + quad * 8];
      const int r0 = (wv * 16 + l15) * 256;
      s8v b0 = *(const s8v*)&Whh_b[(size_t)(     0 + r0) + kt * 32 + quad * 8];
      s8v b1 = *(const s8v*)&Whh_b[(size_t)( 65536 + r0) + kt * 32 + quad * 8];
      s8v b2 = *(const s8v*)&Whh_b[(size_t)(131072 + r0) + kt * 32 + quad * 8];
      s8v b3 = *(const s8v*)&Whh_b[(size_t)(196608 + r0) + kt * 32 + quad * 8];
      ga0 = MFMA16(aA, b0, ga0); ga1 = MFMA16(aA, b1, ga1);
      ga2 = MFMA16(aA, b2, ga2); ga3 = MFMA16(aA, b3, ga3);
    }

    // ---- attention: e[b][n] = Vs + sum_t (-2 V[t]) / (exp2(UxK+whsK)+1) ----
    // pass 0 (batch bq): pure register compute. pass 1 (batch bq+4):
    // nontemporal stream with 1-deep prefetch; first load issued before
    // pass-0 compute so its latency hides under the transcendentals.
    {
      i4v cur = __builtin_nontemporal_load(&ub[ux_base1]);

      const f4v* wvf0 = (const f4v*)&wv_lds[bq * 256];
      float a0 = 0.f, a1 = 0.f, a2 = 0.f, a3 = 0.f;
      att_accum(u0, wvf0, 0, a0, a1, a2, a3);
      att_accum(u1, wvf0, 1, a0, a1, a2, a3);
      att_accum(u2, wvf0, 2, a0, a1, a2, a3);
      att_accum(u3, wvf0, 3, a0, a1, a2, a3);
      att_accum(u4, wvf0, 4, a0, a1, a2, a3);
      att_accum(u5, wvf0, 5, a0, a1, a2, a3);
      att_accum(u6, wvf0, 6, a0, a1, a2, a3);
      att_accum(u7, wvf0, 7, a0, a1, a2, a3);
      {
        float e = Vs + ((a0 + a1) + (a2 + a3));
        e_f[bq * 256 + an] = e;
        float pe = __builtin_amdgcn_exp2f(K1 * e);
        #pragma unroll
        for (int off = 32; off >= 1; off >>= 1) pe += __shfl_xor(pe, off);
        if (lane == 0) Zpart[bq][wv & 3] = pe;
      }

      const f4v* wvf1 = (const f4v*)&wv_lds[(bq + 4) * 256];
      a0 = 0.f; a1 = 0.f; a2 = 0.f; a3 = 0.f;
      #pragma unroll
      for (int tg = 0; tg < 8; tg++) {
        i4v nxt = (tg < 7) ? __builtin_nontemporal_load(&ub[ux_base1 + (size_t)(tg + 1) * 256])
                           : cur;
        att_accum(cur, wvf1, tg, a0, a1, a2, a3);
        cur = nxt;
      }
      {
        float e = Vs + ((a0 + a1) + (a2 + a3));
        e_f[(bq + 4) * 256 + an] = e;
        float pe = __builtin_amdgcn_exp2f(K1 * e);
        #pragma unroll
        for (int off = 32; off >= 1; off >>= 1) pe += __shfl_xor(pe, off);
        if (lane == 0) Zpart[bq + 4][wv & 3] = pe;
      }
    }
    __syncthreads();  // B3: e_f + Zpart ready

    // ---- softmax redistribution + xt (bf16) ----
    {
      const int b8s = tid >> 7;
      const int nn0 = (tid & 127) * 2;
      f4v zp = *(const f4v*)&Zpart[b8s][0];
      float zi = 1.0f / ((zp.x + zp.y) + (zp.z + zp.w));
      float2 ee = *(const float2*)&e_f[b8s * 256 + nn0];
      float p0 = __builtin_amdgcn_exp2f(K1 * ee.x);
      float p1 = __builtin_amdgcn_exp2f(K1 * ee.y);
      unsigned int packed = (unsigned int)f2bf(p0 * zi * ee.x)
                          | ((unsigned int)f2bf(p1 * zi * ee.y) << 16);
      *(unsigned int*)&xt_b[b8s * 264 + nn0] = packed;
    }
    __syncthreads();  // B4: xt ready

    // ---- xt-part of gates ----
    #pragma unroll
    for (int kt = 0; kt < 8; kt++) {
      s8v aA = *(const s8v*)&xt_b[l15 * 264 + kt * 32 + quad * 8];
      const int r0 = (wv * 16 + l15) * 256;
      s8v b0 = *(const s8v*)&Wih_b[(size_t)(     0 + r0) + kt * 32 + quad * 8];
      s8v b1 = *(const s8v*)&Wih_b[(size_t)( 65536 + r0) + kt * 32 + quad * 8];
      s8v b2 = *(const s8v*)&Wih_b[(size_t)(131072 + r0) + kt * 32 + quad * 8];
      s8v b3 = *(const s8v*)&Wih_b[(size_t)(196608 + r0) + kt * 32 + quad * 8];
      ga0 = MFMA16(aA, b0, ga0); ga1 = MFMA16(aA, b1, ga1);
      ga2 = MFMA16(aA, b2, ga2); ga3 = MFMA16(aA, b3, ga3);
    }

    // ---- pointwise LSTM straight from accumulators (lanes 0..31) ----
    if (lane < 32) {
      const int jj = wv * 16 + l15;
      #pragma unroll
      for (int r = 0; r < 4; r++) {
        const int m = quad * 4 + r;
        float iG = ga0[r] + bsum[jj];
        float fG = ga1[r] + bsum[256 + jj];
        float gG = ga2[r] + bsum[512 + jj];
        float oG = ga3[r] + bsum[768 + jj];
        float si = __builtin_amdgcn_rcpf(1.0f + __builtin_amdgcn_exp2f(-K1 * iG));
        float sf = __builtin_amdgcn_rcpf(1.0f + __builtin_amdgcn_exp2f(-K1 * fG));
        float so = __builtin_amdgcn_rcpf(1.0f + __builtin_amdgcn_exp2f(-K1 * oG));
        float tg_ = 1.0f - 2.0f * __builtin_amdgcn_rcpf(1.0f + __builtin_amdgcn_exp2f(K2 * gG));
        float cn = sf * c_f[m * 256 + jj] + si * tg_;
        float th = 1.0f - 2.0f * __builtin_amdgcn_rcpf(1.0f + __builtin_amdgcn_exp2f(K2 * cn));
        float hn = so * th;
        c_f[m * 256 + jj] = cn;
        c_b[m * 264 + jj] = f2bf(cn);
        h_b[m * 264 + jj] = f2bf(hn);
        h_hist[(m * 256 + jj) * 20 + (s & 15)] = f2bf(hn);
      }
    }

    // ---- full-line coalesced output dump every 16 steps (plain stores:
    //      L2 write-back merges the 4x16B into whole 64B lines, no RMW) ----
    if ((s & 15) == 15) {
      __syncthreads();
      #pragma unroll
      for (int p = 0; p < 2; p++) {
        int rid = p * 1024 + tid;
        int mB = rid >> 8, j = rid & 255;
        const us4* hp = (const us4*)&h_hist[rid * 20];
        float* dst = &out[(((size_t)blk * 8 + mB) * 256 + j) * 128 + (s - 15)];
        #pragma unroll
        for (int c = 0; c < 4; c++) {
          us4 u = hp[c];
          f4v o = { bfu(u.x), bfu(u.y), bfu(u.z), bfu(u.w) };
          *(f4v*)(dst + c * 4) = o;
        }
      }
    }
  }
}

extern "C" void kernel_launch(void* const* d_in, const int* in_sizes, int n_in,
                              void* d_out, int out_size, void* d_ws, size_t ws_size,
                              hipStream_t stream) {
  const float* x   = (const float*)d_in[0];
  const float* We  = (const float*)d_in[1];
  const float* Ue  = (const float*)d_in[2];
  const float* Ve  = (const float*)d_in[3];
  const float* Wih = (const float*)d_in[4];
  const float* Whh = (const float*)d_in[5];
  const float* bih = (const float*)d_in[6];
  const float* bhh = (const float*)d_in[7];
  float* out = (float*)d_out;

  char* p = (char*)d_ws;
  unsigned char*  UxK8  = (unsigned char*)p;  p += (size_t)67108864; // 2048*256*128 fp8
  unsigned short* Wih_b = (unsigned short*)p; p += 524288;
  unsigned short* Whh_b = (unsigned short*)p; p += 524288;
  unsigned short* We_b  = (unsigned short*)p; p += 131072;
  unsigned short* Ue_b  = (unsigned short*)p; p += 32768;
  float* bsum = (float*)p;

  prep_kernel<<<512, 256, 0, stream>>>(We, Ue, Wih, Whh, bih, bhh,
                                       Wih_b, Whh_b, We_b, Ue_b, bsum);
  ux_kernel<<<8192, 256, 0, stream>>>(x, Ue_b, UxK8);
  rnn_kernel<<<256, 1024, 0, stream>>>(UxK8, We_b, Wih_b, Whh_b, bsum, Ve, out);
}

// Round 4
// 15752.892 us; speedup vs baseline: 1.0403x; 1.0016x over previous
//
#include <hip/hip_runtime.h>
#include <stdint.h>

typedef short  s8v  __attribute__((ext_vector_type(8)));
typedef float  f4v  __attribute__((ext_vector_type(4)));
typedef float  f2v  __attribute__((ext_vector_type(2)));
typedef int    i4v  __attribute__((ext_vector_type(4)));
typedef unsigned short us4 __attribute__((ext_vector_type(4)));

#define MFMA16(a,b,c) __builtin_amdgcn_mfma_f32_16x16x32_bf16(a,b,c,0,0,0)

#define K1 1.44269504088896340f   /* log2(e)   */
#define K2 2.88539008177792681f   /* 2*log2(e) */

__device__ __forceinline__ unsigned short f2bf(float f) {
  union { float f; uint32_t u; } v; v.f = f;
  return (unsigned short)((v.u + 0x7FFFu + ((v.u >> 16) & 1u)) >> 16);
}
__device__ __forceinline__ float bflo(uint32_t dw) {
  union { uint32_t u; float f; } v; v.u = dw << 16; return v.f;
}
__device__ __forceinline__ float bfhi(uint32_t dw) {
  union { uint32_t u; float f; } v; v.u = dw & 0xFFFF0000u; return v.f;
}
__device__ __forceinline__ float bfu(unsigned short u) {
  union { uint32_t u; float f; } v; v.u = ((uint32_t)u) << 16; return v.f;
}

// one 16-t chunk of the attention sum; tg must be a compile-time constant at
// every call site so the wv_lds indices stay static.
__device__ __forceinline__ void att_accum(i4v cur, const f4v* __restrict__ wvf, int tg,
                                          float& a0, float& a1, float& a2, float& a3) {
  #pragma unroll
  for (int q = 0; q < 4; q++) {
    uint32_t dw = (uint32_t)cur[q];
    f2v lo = __builtin_amdgcn_cvt_pk_f32_fp8(dw, 0);
    f2v hi = __builtin_amdgcn_cvt_pk_f32_fp8(dw, 1);
    const int t = tg * 16 + q * 4;
    f4v w01 = wvf[(t >> 1)];       // (whs_t, -2V_t, whs_t+1, -2V_t+1)
    f4v w23 = wvf[(t >> 1) + 1];
    float x0 = lo.x + w01.x;
    a0 = fmaf(w01.y, __builtin_amdgcn_rcpf(__builtin_amdgcn_exp2f(x0) + 1.0f), a0);
    float x1 = lo.y + w01.z;
    a1 = fmaf(w01.w, __builtin_amdgcn_rcpf(__builtin_amdgcn_exp2f(x1) + 1.0f), a1);
    float x2 = hi.x + w23.x;
    a2 = fmaf(w23.y, __builtin_amdgcn_rcpf(__builtin_amdgcn_exp2f(x2) + 1.0f), a2);
    float x3 = hi.y + w23.z;
    a3 = fmaf(w23.w, __builtin_amdgcn_rcpf(__builtin_amdgcn_exp2f(x3) + 1.0f), a3);
  }
}

// ---------------- prep: convert weights to bf16, sum biases ----------------
__global__ __launch_bounds__(256) void prep_kernel(
    const float* __restrict__ We, const float* __restrict__ Ue,
    const float* __restrict__ Wih, const float* __restrict__ Whh,
    const float* __restrict__ bih, const float* __restrict__ bhh,
    unsigned short* __restrict__ Wih_b, unsigned short* __restrict__ Whh_b,
    unsigned short* __restrict__ We_b, unsigned short* __restrict__ Ue_b,
    float* __restrict__ bsum)
{
  int i0 = blockIdx.x * 256 + threadIdx.x;
  int stride = gridDim.x * 256;
  for (int i = i0; i < 262144; i += stride) Wih_b[i] = f2bf(Wih[i]);
  for (int i = i0; i < 262144; i += stride) Whh_b[i] = f2bf(Whh[i]);
  for (int i = i0; i < 65536;  i += stride) We_b[i]  = f2bf(We[i]);
  for (int i = i0; i < 16384;  i += stride) Ue_b[i]  = f2bf(Ue[i]);
  for (int i = i0; i < 1024;   i += stride) bsum[i]  = bih[i] + bhh[i];
}

// ---- Ux GEMM: UxK8[b][tg][n][16] = fp8(K2 * sum_t x[b][t][n]*U_e[s][t]) ----
// layout: b*2048 + tg*256 + n  (16-byte units, 16 t per chunk)
__global__ __launch_bounds__(256) void ux_kernel(
    const float* __restrict__ x, const unsigned short* __restrict__ Ue_b,
    unsigned char* __restrict__ UxK8)
{
  __shared__ unsigned short xT[64 * 136];  // x[b][t][n] -> [n][t], padded
  __shared__ unsigned short oT[64 * 136];  // result rows n, cols s (bf16)
  const int tid = threadIdx.x;
  const int b   = blockIdx.x >> 2;
  const int n0  = (blockIdx.x & 3) * 64;

  {
    const int nl = tid & 63, tp = tid >> 6;
    for (int i = 0; i < 32; i++) {
      int t = tp + i * 4;
      xT[nl * 136 + t] = f2bf(x[((size_t)b * 128 + t) * 256 + n0 + nl]);
    }
  }
  __syncthreads();
  {
    const int w = tid >> 6, lane = tid & 63;
    const int l15 = lane & 15, quad = lane >> 4;
    for (int tt = 0; tt < 8; tt++) {
      f4v acc = {0.f, 0.f, 0.f, 0.f};
      #pragma unroll
      for (int kt = 0; kt < 4; kt++) {
        s8v a  = *(const s8v*)&xT[(w * 16 + l15) * 136 + kt * 32 + quad * 8];
        s8v bb = *(const s8v*)&Ue_b[(tt * 16 + l15) * 128 + kt * 32 + quad * 8];
        acc = MFMA16(a, bb, acc);
      }
      #pragma unroll
      for (int r = 0; r < 4; r++)
        oT[(w * 16 + quad * 4 + r) * 136 + tt * 16 + l15] = f2bf(acc[r] * K2);
    }
  }
  __syncthreads();
  {
    for (int p = 0; p < 2; p++) {
      int row = (tid >> 3) + p * 32;   // local n
      int tg  = tid & 7;               // 16-t chunk
      const unsigned int* sp = (const unsigned int*)&oT[row * 136 + tg * 16];
      i4v outv;
      #pragma unroll
      for (int j = 0; j < 4; j++) {
        unsigned int d0 = sp[2 * j], d1 = sp[2 * j + 1];
        int w = __builtin_amdgcn_cvt_pk_fp8_f32(bflo(d0), bfhi(d0), 0, 0);
        w     = __builtin_amdgcn_cvt_pk_fp8_f32(bflo(d1), bfhi(d1), w, 1);
        outv[j] = w;
      }
      *(i4v*)&UxK8[(((size_t)b * 8 + tg) * 256 + n0 + row) * 16] = outv;
    }
  }
}

// ---------------- persistent recurrence: 256 blocks x 1024 thr, 8 batch/blk --
// amdgpu_waves_per_eu(4,4): LDS=136KB forces 1 block/CU = 4 waves/SIMD, so the
// only achievable occupancy IS 4/EU. Pinning min=max=4 gives RA the full
// 128-VGPR budget; without it the allocator targeted 64 VGPRs (8/EU-compat)
// and spilled/sank the persistent UxK8 slice (rounds 2-3: +8GB FETCH).
__global__ __launch_bounds__(1024)
__attribute__((amdgpu_waves_per_eu(4, 4)))
void rnn_kernel(
    const unsigned char* __restrict__ UxK8,
    const unsigned short* __restrict__ We_b,
    const unsigned short* __restrict__ Wih_b,
    const unsigned short* __restrict__ Whh_b,
    const float* __restrict__ bsum_g,
    const float* __restrict__ Ve,
    float* __restrict__ out)
{
  __shared__ unsigned short h_hist[2048 * 20];  // 80 KB: bf16 h, depth 16, stride 20
  __shared__ unsigned short xt_b[16 * 264];     // bf16, rows 8..15 zero-pad
  __shared__ unsigned short h_b [16 * 264];
  __shared__ unsigned short c_b [16 * 264];
  __shared__ float  c_f[8 * 256];               // f32 cell state
  __shared__ float  e_f[8 * 256];
  __shared__ float  wv_lds[8 * 128 * 2];        // [b][t] -> (K2*whs, -2*V)
  __shared__ float  bsum[1024];
  __shared__ float  Zpart[8][4];

  const int tid  = threadIdx.x;
  const int wv   = tid >> 6;
  const int lane = tid & 63;
  const int l15  = lane & 15;
  const int quad = lane >> 4;
  const int blk  = blockIdx.x;

  for (int i = tid; i < 16 * 264; i += 1024) { xt_b[i] = 0; h_b[i] = 0; c_b[i] = 0; }
  for (int i = tid; i < 2048; i += 1024) c_f[i] = 0.f;
  bsum[tid] = bsum_g[tid];
  {
    int b8 = tid >> 7, t = tid & 127;
    wv_lds[(b8 * 128 + t) * 2 + 1] = -2.0f * Ve[t];
    wv_lds[(b8 * 128 + t) * 2 + 0] = 0.f;
  }
  float Vs = 0.f;
  for (int t = 0; t < 128; t++) Vs += Ve[t];
  __syncthreads();

  const int an = tid & 255;   // n index owned by this thread
  const int bq = tid >> 8;    // handles batches bq and bq+4

  const i4v* ub = (const i4v*)UxK8;
  const size_t ux_base0 = ((size_t)(blk * 8 + bq)    ) * 2048 + an;
  const size_t ux_base1 = ((size_t)(blk * 8 + bq + 4)) * 2048 + an;

  // Both batches' loop-invariant UxK8 slices live in 16 NAMED i4v registers
  // (64 VGPRs) for the entire recurrence. The empty-asm "pin" makes them
  // opaque register values the compiler cannot re-derive from memory
  // (prevents the round-3 load-sinking). Eliminates the 8.6 GB/run re-read
  // and the L2 thrash that evicted the gate weights every step.
  i4v u0 = ub[ux_base0];
  i4v u1 = ub[ux_base0 + 256];
  i4v u2 = ub[ux_base0 + 512];
  i4v u3 = ub[ux_base0 + 768];
  i4v u4 = ub[ux_base0 + 1024];
  i4v u5 = ub[ux_base0 + 1280];
  i4v u6 = ub[ux_base0 + 1536];
  i4v u7 = ub[ux_base0 + 1792];
  i4v w0 = ub[ux_base1];
  i4v w1 = ub[ux_base1 + 256];
  i4v w2 = ub[ux_base1 + 512];
  i4v w3 = ub[ux_base1 + 768];
  i4v w4 = ub[ux_base1 + 1024];
  i4v w5 = ub[ux_base1 + 1280];
  i4v w6 = ub[ux_base1 + 1536];
  i4v w7 = ub[ux_base1 + 1792];
  asm volatile("" : "+v"(u0), "+v"(u1), "+v"(u2), "+v"(u3),
                    "+v"(u4), "+v"(u5), "+v"(u6), "+v"(u7));
  asm volatile("" : "+v"(w0), "+v"(w1), "+v"(w2), "+v"(w3),
                    "+v"(w4), "+v"(w5), "+v"(w6), "+v"(w7));

  f4v ga0, ga1, ga2, ga3;

  for (int s = 0; s < 128; s++) {
    __syncthreads();   // B1: h_b/c_b stable from previous step

    // ---- whs = [h,c] @ W_e.T  (waves 0..7, t-tile = wv) ----
    if (wv < 8) {
      f4v acc = {0.f, 0.f, 0.f, 0.f};
      #pragma unroll
      for (int kt = 0; kt < 8; kt++) {
        s8v a  = *(const s8v*)&h_b[l15 * 264 + kt * 32 + quad * 8];
        s8v bb = *(const s8v*)&We_b[(wv * 16 + l15) * 512 + kt * 32 + quad * 8];
        acc = MFMA16(a, bb, acc);
      }
      #pragma unroll
      for (int kt = 0; kt < 8; kt++) {
        s8v a  = *(const s8v*)&c_b[l15 * 264 + kt * 32 + quad * 8];
        s8v bb = *(const s8v*)&We_b[(wv * 16 + l15) * 512 + 256 + kt * 32 + quad * 8];
        acc = MFMA16(a, bb, acc);
      }
      if (lane < 32) {
        #pragma unroll
        for (int r = 0; r < 4; r++)
          wv_lds[((quad * 4 + r) * 128 + wv * 16 + l15) * 2] = K2 * acc[r];
      }
    }
    __syncthreads();   // B2: whsK ready

    // ---- h-part of gates (all 16 waves), single-kt to bound VGPR pressure ----
    ga0 = (f4v){0.f,0.f,0.f,0.f}; ga1 = ga0; ga2 = ga0; ga3 = ga0;
    #pragma unroll
    for (int kt = 0; kt < 8; kt++) {
      s8v aA = *(const s8v*)&h_b[l15 * 264 + kt * 32 + quad * 8];
      const int r0 = (wv * 16 + l15) * 256;
      s8v b0 = *(const s8v*)&Whh_b[(size_t)(     0 + r0) + kt * 32 + quad * 8];
      s8v b1 = *(const s8v*)&Whh_b[(size_t)( 65536 + r0) + kt * 32 + quad * 8];
      s8v b2 = *(const s8v*)&Whh_b[(size_t)(131072 + r0) + kt * 32 + quad * 8];
      s8v b3 = *(const s8v*)&Whh_b[(size_t)(196608 + r0) + kt * 32 + quad * 8];
      ga0 = MFMA16(aA, b0, ga0); ga1 = MFMA16(aA, b1, ga1);
      ga2 = MFMA16(aA, b2, ga2); ga3 = MFMA16(aA, b3, ga3);
    }

    // ---- attention: e[b][n] = Vs + sum_t (-2 V[t]) / (exp2(UxK+whsK)+1) ----
    // All UxK values register-resident: zero global loads in this phase.
    {
      const f4v* wvf0 = (const f4v*)&wv_lds[bq * 256];
      float a0 = 0.f, a1 = 0.f, a2 = 0.f, a3 = 0.f;
      att_accum(u0, wvf0, 0, a0, a1, a2, a3);
      att_accum(u1, wvf0, 1, a0, a1, a2, a3);
      att_accum(u2, wvf0, 2, a0, a1, a2, a3);
      att_accum(u3, wvf0, 3, a0, a1, a2, a3);
      att_accum(u4, wvf0, 4, a0, a1, a2, a3);
      att_accum(u5, wvf0, 5, a0, a1, a2, a3);
      att_accum(u6, wvf0, 6, a0, a1, a2, a3);
      att_accum(u7, wvf0, 7, a0, a1, a2, a3);
      {
        float e = Vs + ((a0 + a1) + (a2 + a3));
        e_f[bq * 256 + an] = e;
        float pe = __builtin_amdgcn_exp2f(K1 * e);
        #pragma unroll
        for (int off = 32; off >= 1; off >>= 1) pe += __shfl_xor(pe, off);
        if (lane == 0) Zpart[bq][wv & 3] = pe;
      }

      const f4v* wvf1 = (const f4v*)&wv_lds[(bq + 4) * 256];
      a0 = 0.f; a1 = 0.f; a2 = 0.f; a3 = 0.f;
      att_accum(w0, wvf1, 0, a0, a1, a2, a3);
      att_accum(w1, wvf1, 1, a0, a1, a2, a3);
      att_accum(w2, wvf1, 2, a0, a1, a2, a3);
      att_accum(w3, wvf1, 3, a0, a1, a2, a3);
      att_accum(w4, wvf1, 4, a0, a1, a2, a3);
      att_accum(w5, wvf1, 5, a0, a1, a2, a3);
      att_accum(w6, wvf1, 6, a0, a1, a2, a3);
      att_accum(w7, wvf1, 7, a0, a1, a2, a3);
      {
        float e = Vs + ((a0 + a1) + (a2 + a3));
        e_f[(bq + 4) * 256 + an] = e;
        float pe = __builtin_amdgcn_exp2f(K1 * e);
        #pragma unroll
        for (int off = 32; off >= 1; off >>= 1) pe += __shfl_xor(pe, off);
        if (lane == 0) Zpart[bq + 4][wv & 3] = pe;
      }
    }
    __syncthreads();  // B3: e_f + Zpart ready

    // ---- softmax redistribution + xt (bf16) ----
    {
      const int b8s = tid >> 7;
      const int nn0 = (tid & 127) * 2;
      f4v zp = *(const f4v*)&Zpart[b8s][0];
      float zi = 1.0f / ((zp.x + zp.y) + (zp.z + zp.w));
      float2 ee = *(const float2*)&e_f[b8s * 256 + nn0];
      float p0 = __builtin_amdgcn_exp2f(K1 * ee.x);
      float p1 = __builtin_amdgcn_exp2f(K1 * ee.y);
      unsigned int packed = (unsigned int)f2bf(p0 * zi * ee.x)
                          | ((unsigned int)f2bf(p1 * zi * ee.y) << 16);
      *(unsigned int*)&xt_b[b8s * 264 + nn0] = packed;
    }
    __syncthreads();  // B4: xt ready

    // ---- xt-part of gates ----
    #pragma unroll
    for (int kt = 0; kt < 8; kt++) {
      s8v aA = *(const s8v*)&xt_b[l15 * 264 + kt * 32 + quad * 8];
      const int r0 = (wv * 16 + l15) * 256;
      s8v b0 = *(const s8v*)&Wih_b[(size_t)(     0 + r0) + kt * 32 + quad * 8];
      s8v b1 = *(const s8v*)&Wih_b[(size_t)( 65536 + r0) + kt * 32 + quad * 8];
      s8v b2 = *(const s8v*)&Wih_b[(size_t)(131072 + r0) + kt * 32 + quad * 8];
      s8v b3 = *(const s8v*)&Wih_b[(size_t)(196608 + r0) + kt * 32 + quad * 8];
      ga0 = MFMA16(aA, b0, ga0); ga1 = MFMA16(aA, b1, ga1);
      ga2 = MFMA16(aA, b2, ga2); ga3 = MFMA16(aA, b3, ga3);
    }

    // ---- pointwise LSTM straight from accumulators (lanes 0..31) ----
    if (lane < 32) {
      const int jj = wv * 16 + l15;
      #pragma unroll
      for (int r = 0; r < 4; r++) {
        const int m = quad * 4 + r;
        float iG = ga0[r] + bsum[jj];
        float fG = ga1[r] + bsum[256 + jj];
        float gG = ga2[r] + bsum[512 + jj];
        float oG = ga3[r] + bsum[768 + jj];
        float si = __builtin_amdgcn_rcpf(1.0f + __builtin_amdgcn_exp2f(-K1 * iG));
        float sf = __builtin_amdgcn_rcpf(1.0f + __builtin_amdgcn_exp2f(-K1 * fG));
        float so = __builtin_amdgcn_rcpf(1.0f + __builtin_amdgcn_exp2f(-K1 * oG));
        float tg_ = 1.0f - 2.0f * __builtin_amdgcn_rcpf(1.0f + __builtin_amdgcn_exp2f(K2 * gG));
        float cn = sf * c_f[m * 256 + jj] + si * tg_;
        float th = 1.0f - 2.0f * __builtin_amdgcn_rcpf(1.0f + __builtin_amdgcn_exp2f(K2 * cn));
        float hn = so * th;
        c_f[m * 256 + jj] = cn;
        c_b[m * 264 + jj] = f2bf(cn);
        h_b[m * 264 + jj] = f2bf(hn);
        h_hist[(m * 256 + jj) * 20 + (s & 15)] = f2bf(hn);
      }
    }

    // ---- full-line coalesced output dump every 16 steps (plain stores:
    //      L2 write-back merges the 4x16B into whole 64B lines, no RMW) ----
    if ((s & 15) == 15) {
      __syncthreads();
      #pragma unroll
      for (int p = 0; p < 2; p++) {
        int rid = p * 1024 + tid;
        int mB = rid >> 8, j = rid & 255;
        const us4* hp = (const us4*)&h_hist[rid * 20];
        float* dst = &out[(((size_t)blk * 8 + mB) * 256 + j) * 128 + (s - 15)];
        #pragma unroll
        for (int c = 0; c < 4; c++) {
          us4 u = hp[c];
          f4v o = { bfu(u.x), bfu(u.y), bfu(u.z), bfu(u.w) };
          *(f4v*)(dst + c * 4) = o;
        }
      }
    }
  }
}

extern "C" void kernel_launch(void* const* d_in, const int* in_sizes, int n_in,
                              void* d_out, int out_size, void* d_ws, size_t ws_size,
                              hipStream_t stream) {
  const float* x   = (const float*)d_in[0];
  const float* We  = (const float*)d_in[1];
  const float* Ue  = (const float*)d_in[2];
  const float* Ve  = (const float*)d_in[3];
  const float* Wih = (const float*)d_in[4];
  const float* Whh = (const float*)d_in[5];
  const float* bih = (const float*)d_in[6];
  const float* bhh = (const float*)d_in[7];
  float* out = (float*)d_out;

  char* p = (char*)d_ws;
  unsigned char*  UxK8  = (unsigned char*)p;  p += (size_t)67108864; // 2048*256*128 fp8
  unsigned short* Wih_b = (unsigned short*)p; p += 524288;
  unsigned short* Whh_b = (unsigned short*)p; p += 524288;
  unsigned short* We_b  = (unsigned short*)p; p += 131072;
  unsigned short* Ue_b  = (unsigned short*)p; p += 32768;
  float* bsum = (float*)p;

  prep_kernel<<<512, 256, 0, stream>>>(We, Ue, Wih, Whh, bih, bhh,
                                       Wih_b, Whh_b, We_b, Ue_b, bsum);
  ux_kernel<<<8192, 256, 0, stream>>>(x, Ue_b, UxK8);
  rnn_kernel<<<256, 1024, 0, stream>>>(UxK8, We_b, Wih_b, Whh_b, bsum, Ve, out);
}

// Round 5
// 10551.704 us; speedup vs baseline: 1.5531x; 1.4929x over previous
//
#include <hip/hip_runtime.h>
#include <stdint.h>

typedef short  s8v  __attribute__((ext_vector_type(8)));
typedef float  f4v  __attribute__((ext_vector_type(4)));
typedef float  f2v  __attribute__((ext_vector_type(2)));
typedef int    i4v  __attribute__((ext_vector_type(4)));
typedef unsigned short us4 __attribute__((ext_vector_type(4)));

#define MFMA16(a,b,c) __builtin_amdgcn_mfma_f32_16x16x32_bf16(a,b,c,0,0,0)

#define K1 1.44269504088896340f   /* log2(e)   */
#define K2 2.88539008177792681f   /* 2*log2(e) */

__device__ __forceinline__ unsigned short f2bf(float f) {
  union { float f; uint32_t u; } v; v.f = f;
  return (unsigned short)((v.u + 0x7FFFu + ((v.u >> 16) & 1u)) >> 16);
}
__device__ __forceinline__ float bflo(uint32_t dw) {
  union { uint32_t u; float f; } v; v.u = dw << 16; return v.f;
}
__device__ __forceinline__ float bfhi(uint32_t dw) {
  union { uint32_t u; float f; } v; v.u = dw & 0xFFFF0000u; return v.f;
}
__device__ __forceinline__ float bfu(unsigned short u) {
  union { uint32_t u; float f; } v; v.u = ((uint32_t)u) << 16; return v.f;
}

// ---- AGPR stash: the unified gfx950 register file is split ~64 arch /
// 64 accum for MFMA kernels at the 4-waves/SIMD budget. The arch half is
// the allocator's hard 64-VGPR target (rounds 2-4: every persistent value
// beyond it was spilled to scratch, +8 GB FETCH). The accum half is mostly
// idle (~16 regs of MFMA accumulators). Pin the loop-invariant UxK8 slice
// there with explicit accvgpr moves; "a"-constrained asm values cannot be
// rematerialized or silently spilled by the arch-VGPR heuristic.
__device__ __forceinline__ void agpr_w(int& a, int v) {
  asm volatile("v_accvgpr_write_b32 %0, %1" : "=a"(a) : "v"(v));
}
__device__ __forceinline__ int agpr_r(int& a) {
  int v;
  asm volatile("v_accvgpr_read_b32 %0, %1" : "=v"(v) : "a"(a));
  return v;
}
#define DECL_STASH(nm) int nm##_0, nm##_1, nm##_2, nm##_3
#define STASH(nm, vec) do { i4v _t = (vec); \
  agpr_w(nm##_0, _t[0]); agpr_w(nm##_1, _t[1]); \
  agpr_w(nm##_2, _t[2]); agpr_w(nm##_3, _t[3]); } while (0)
#define LOAD4(nm) __extension__({ i4v _c; \
  _c[0] = agpr_r(nm##_0); _c[1] = agpr_r(nm##_1); \
  _c[2] = agpr_r(nm##_2); _c[3] = agpr_r(nm##_3); _c; })

// one 16-t chunk of the attention sum; tg must be a compile-time constant at
// every call site so the wv_lds indices stay static.
__device__ __forceinline__ void att_accum(i4v cur, const f4v* __restrict__ wvf, int tg,
                                          float& a0, float& a1, float& a2, float& a3) {
  #pragma unroll
  for (int q = 0; q < 4; q++) {
    uint32_t dw = (uint32_t)cur[q];
    f2v lo = __builtin_amdgcn_cvt_pk_f32_fp8(dw, 0);
    f2v hi = __builtin_amdgcn_cvt_pk_f32_fp8(dw, 1);
    const int t = tg * 16 + q * 4;
    f4v w01 = wvf[(t >> 1)];       // (whs_t, -2V_t, whs_t+1, -2V_t+1)
    f4v w23 = wvf[(t >> 1) + 1];
    float x0 = lo.x + w01.x;
    a0 = fmaf(w01.y, __builtin_amdgcn_rcpf(__builtin_amdgcn_exp2f(x0) + 1.0f), a0);
    float x1 = lo.y + w01.z;
    a1 = fmaf(w01.w, __builtin_amdgcn_rcpf(__builtin_amdgcn_exp2f(x1) + 1.0f), a1);
    float x2 = hi.x + w23.x;
    a2 = fmaf(w23.y, __builtin_amdgcn_rcpf(__builtin_amdgcn_exp2f(x2) + 1.0f), a2);
    float x3 = hi.y + w23.z;
    a3 = fmaf(w23.w, __builtin_amdgcn_rcpf(__builtin_amdgcn_exp2f(x3) + 1.0f), a3);
  }
}

// ---------------- prep: convert weights to bf16, sum biases ----------------
__global__ __launch_bounds__(256) void prep_kernel(
    const float* __restrict__ We, const float* __restrict__ Ue,
    const float* __restrict__ Wih, const float* __restrict__ Whh,
    const float* __restrict__ bih, const float* __restrict__ bhh,
    unsigned short* __restrict__ Wih_b, unsigned short* __restrict__ Whh_b,
    unsigned short* __restrict__ We_b, unsigned short* __restrict__ Ue_b,
    float* __restrict__ bsum)
{
  int i0 = blockIdx.x * 256 + threadIdx.x;
  int stride = gridDim.x * 256;
  for (int i = i0; i < 262144; i += stride) Wih_b[i] = f2bf(Wih[i]);
  for (int i = i0; i < 262144; i += stride) Whh_b[i] = f2bf(Whh[i]);
  for (int i = i0; i < 65536;  i += stride) We_b[i]  = f2bf(We[i]);
  for (int i = i0; i < 16384;  i += stride) Ue_b[i]  = f2bf(Ue[i]);
  for (int i = i0; i < 1024;   i += stride) bsum[i]  = bih[i] + bhh[i];
}

// ---- Ux GEMM: UxK8[b][tg][n][16] = fp8(K2 * sum_t x[b][t][n]*U_e[s][t]) ----
// layout: b*2048 + tg*256 + n  (16-byte units, 16 t per chunk)
__global__ __launch_bounds__(256) void ux_kernel(
    const float* __restrict__ x, const unsigned short* __restrict__ Ue_b,
    unsigned char* __restrict__ UxK8)
{
  __shared__ unsigned short xT[64 * 136];  // x[b][t][n] -> [n][t], padded
  __shared__ unsigned short oT[64 * 136];  // result rows n, cols s (bf16)
  const int tid = threadIdx.x;
  const int b   = blockIdx.x >> 2;
  const int n0  = (blockIdx.x & 3) * 64;

  {
    const int nl = tid & 63, tp = tid >> 6;
    for (int i = 0; i < 32; i++) {
      int t = tp + i * 4;
      xT[nl * 136 + t] = f2bf(x[((size_t)b * 128 + t) * 256 + n0 + nl]);
    }
  }
  __syncthreads();
  {
    const int w = tid >> 6, lane = tid & 63;
    const int l15 = lane & 15, quad = lane >> 4;
    for (int tt = 0; tt < 8; tt++) {
      f4v acc = {0.f, 0.f, 0.f, 0.f};
      #pragma unroll
      for (int kt = 0; kt < 4; kt++) {
        s8v a  = *(const s8v*)&xT[(w * 16 + l15) * 136 + kt * 32 + quad * 8];
        s8v bb = *(const s8v*)&Ue_b[(tt * 16 + l15) * 128 + kt * 32 + quad * 8];
        acc = MFMA16(a, bb, acc);
      }
      #pragma unroll
      for (int r = 0; r < 4; r++)
        oT[(w * 16 + quad * 4 + r) * 136 + tt * 16 + l15] = f2bf(acc[r] * K2);
    }
  }
  __syncthreads();
  {
    for (int p = 0; p < 2; p++) {
      int row = (tid >> 3) + p * 32;   // local n
      int tg  = tid & 7;               // 16-t chunk
      const unsigned int* sp = (const unsigned int*)&oT[row * 136 + tg * 16];
      i4v outv;
      #pragma unroll
      for (int j = 0; j < 4; j++) {
        unsigned int d0 = sp[2 * j], d1 = sp[2 * j + 1];
        int w = __builtin_amdgcn_cvt_pk_fp8_f32(bflo(d0), bfhi(d0), 0, 0);
        w     = __builtin_amdgcn_cvt_pk_fp8_f32(bflo(d1), bfhi(d1), w, 1);
        outv[j] = w;
      }
      *(i4v*)&UxK8[(((size_t)b * 8 + tg) * 256 + n0 + row) * 16] = outv;
    }
  }
}

// ---------------- persistent recurrence: 256 blocks x 1024 thr, 8 batch/blk --
__global__ __launch_bounds__(1024, 4) void rnn_kernel(
    const unsigned char* __restrict__ UxK8,
    const unsigned short* __restrict__ We_b,
    const unsigned short* __restrict__ Wih_b,
    const unsigned short* __restrict__ Whh_b,
    const float* __restrict__ bsum_g,
    const float* __restrict__ Ve,
    float* __restrict__ out)
{
  __shared__ unsigned short h_hist[2048 * 20];  // 80 KB: bf16 h, depth 16, stride 20
  __shared__ unsigned short xt_b[16 * 264];     // bf16, rows 8..15 zero-pad
  __shared__ unsigned short h_b [16 * 264];
  __shared__ unsigned short c_b [16 * 264];
  __shared__ float  c_f[8 * 256];               // f32 cell state
  __shared__ float  e_f[8 * 256];
  __shared__ float  wv_lds[8 * 128 * 2];        // [b][t] -> (K2*whs, -2*V)
  __shared__ float  bsum[1024];
  __shared__ float  Zpart[8][4];

  const int tid  = threadIdx.x;
  const int wv   = tid >> 6;
  const int lane = tid & 63;
  const int l15  = lane & 15;
  const int quad = lane >> 4;
  const int blk  = blockIdx.x;

  for (int i = tid; i < 16 * 264; i += 1024) { xt_b[i] = 0; h_b[i] = 0; c_b[i] = 0; }
  for (int i = tid; i < 2048; i += 1024) c_f[i] = 0.f;
  bsum[tid] = bsum_g[tid];
  {
    int b8 = tid >> 7, t = tid & 127;
    wv_lds[(b8 * 128 + t) * 2 + 1] = -2.0f * Ve[t];
    wv_lds[(b8 * 128 + t) * 2 + 0] = 0.f;
  }
  float Vs = 0.f;
  for (int t = 0; t < 128; t++) Vs += Ve[t];
  __syncthreads();

  const int an = tid & 255;   // n index owned by this thread
  const int bq = tid >> 8;    // handles batches bq and bq+4

  const i4v* ub = (const i4v*)UxK8;
  const size_t ux_base0 = ((size_t)(blk * 8 + bq)    ) * 2048 + an;
  const size_t ux_base1 = ((size_t)(blk * 8 + bq + 4)) * 2048 + an;

  // Both batches' loop-invariant UxK8 slices -> 64 dwords in the accum bank.
  DECL_STASH(u0); DECL_STASH(u1); DECL_STASH(u2); DECL_STASH(u3);
  DECL_STASH(u4); DECL_STASH(u5); DECL_STASH(u6); DECL_STASH(u7);
  DECL_STASH(w0); DECL_STASH(w1); DECL_STASH(w2); DECL_STASH(w3);
  DECL_STASH(w4); DECL_STASH(w5); DECL_STASH(w6); DECL_STASH(w7);
  STASH(u0, ub[ux_base0]);
  STASH(u1, ub[ux_base0 + 256]);
  STASH(u2, ub[ux_base0 + 512]);
  STASH(u3, ub[ux_base0 + 768]);
  STASH(u4, ub[ux_base0 + 1024]);
  STASH(u5, ub[ux_base0 + 1280]);
  STASH(u6, ub[ux_base0 + 1536]);
  STASH(u7, ub[ux_base0 + 1792]);
  STASH(w0, ub[ux_base1]);
  STASH(w1, ub[ux_base1 + 256]);
  STASH(w2, ub[ux_base1 + 512]);
  STASH(w3, ub[ux_base1 + 768]);
  STASH(w4, ub[ux_base1 + 1024]);
  STASH(w5, ub[ux_base1 + 1280]);
  STASH(w6, ub[ux_base1 + 1536]);
  STASH(w7, ub[ux_base1 + 1792]);

  f4v ga0, ga1, ga2, ga3;

  for (int s = 0; s < 128; s++) {
    __syncthreads();   // B1: h_b/c_b stable from previous step

    // ---- whs = [h,c] @ W_e.T  (waves 0..7, t-tile = wv) ----
    if (wv < 8) {
      f4v acc = {0.f, 0.f, 0.f, 0.f};
      #pragma unroll
      for (int kt = 0; kt < 8; kt++) {
        s8v a  = *(const s8v*)&h_b[l15 * 264 + kt * 32 + quad * 8];
        s8v bb = *(const s8v*)&We_b[(wv * 16 + l15) * 512 + kt * 32 + quad * 8];
        acc = MFMA16(a, bb, acc);
      }
      #pragma unroll
      for (int kt = 0; kt < 8; kt++) {
        s8v a  = *(const s8v*)&c_b[l15 * 264 + kt * 32 + quad * 8];
        s8v bb = *(const s8v*)&We_b[(wv * 16 + l15) * 512 + 256 + kt * 32 + quad * 8];
        acc = MFMA16(a, bb, acc);
      }
      if (lane < 32) {
        #pragma unroll
        for (int r = 0; r < 4; r++)
          wv_lds[((quad * 4 + r) * 128 + wv * 16 + l15) * 2] = K2 * acc[r];
      }
    }
    __syncthreads();   // B2: whsK ready

    // ---- h-part of gates (all 16 waves), single-kt to bound VGPR pressure ----
    ga0 = (f4v){0.f,0.f,0.f,0.f}; ga1 = ga0; ga2 = ga0; ga3 = ga0;
    #pragma unroll
    for (int kt = 0; kt < 8; kt++) {
      s8v aA = *(const s8v*)&h_b[l15 * 264 + kt * 32 + quad * 8];
      const int r0 = (wv * 16 + l15) * 256;
      s8v b0 = *(const s8v*)&Whh_b[(size_t)(     0 + r0) + kt * 32 + quad * 8];
      s8v b1 = *(const s8v*)&Whh_b[(size_t)( 65536 + r0) + kt * 32 + quad * 8];
      s8v b2 = *(const s8v*)&Whh_b[(size_t)(131072 + r0) + kt * 32 + quad * 8];
      s8v b3 = *(const s8v*)&Whh_b[(size_t)(196608 + r0) + kt * 32 + quad * 8];
      ga0 = MFMA16(aA, b0, ga0); ga1 = MFMA16(aA, b1, ga1);
      ga2 = MFMA16(aA, b2, ga2); ga3 = MFMA16(aA, b3, ga3);
    }

    // ---- attention: e[b][n] = Vs + sum_t (-2 V[t]) / (exp2(UxK+whsK)+1) ----
    // UxK comes back from the accum bank 4 dwords at a time: zero global
    // loads, zero scratch, bounded arch-VGPR pressure.
    {
      const f4v* wvf0 = (const f4v*)&wv_lds[bq * 256];
      float a0 = 0.f, a1 = 0.f, a2 = 0.f, a3 = 0.f;
      att_accum(LOAD4(u0), wvf0, 0, a0, a1, a2, a3);
      att_accum(LOAD4(u1), wvf0, 1, a0, a1, a2, a3);
      att_accum(LOAD4(u2), wvf0, 2, a0, a1, a2, a3);
      att_accum(LOAD4(u3), wvf0, 3, a0, a1, a2, a3);
      att_accum(LOAD4(u4), wvf0, 4, a0, a1, a2, a3);
      att_accum(LOAD4(u5), wvf0, 5, a0, a1, a2, a3);
      att_accum(LOAD4(u6), wvf0, 6, a0, a1, a2, a3);
      att_accum(LOAD4(u7), wvf0, 7, a0, a1, a2, a3);
      {
        float e = Vs + ((a0 + a1) + (a2 + a3));
        e_f[bq * 256 + an] = e;
        float pe = __builtin_amdgcn_exp2f(K1 * e);
        #pragma unroll
        for (int off = 32; off >= 1; off >>= 1) pe += __shfl_xor(pe, off);
        if (lane == 0) Zpart[bq][wv & 3] = pe;
      }

      const f4v* wvf1 = (const f4v*)&wv_lds[(bq + 4) * 256];
      a0 = 0.f; a1 = 0.f; a2 = 0.f; a3 = 0.f;
      att_accum(LOAD4(w0), wvf1, 0, a0, a1, a2, a3);
      att_accum(LOAD4(w1), wvf1, 1, a0, a1, a2, a3);
      att_accum(LOAD4(w2), wvf1, 2, a0, a1, a2, a3);
      att_accum(LOAD4(w3), wvf1, 3, a0, a1, a2, a3);
      att_accum(LOAD4(w4), wvf1, 4, a0, a1, a2, a3);
      att_accum(LOAD4(w5), wvf1, 5, a0, a1, a2, a3);
      att_accum(LOAD4(w6), wvf1, 6, a0, a1, a2, a3);
      att_accum(LOAD4(w7), wvf1, 7, a0, a1, a2, a3);
      {
        float e = Vs + ((a0 + a1) + (a2 + a3));
        e_f[(bq + 4) * 256 + an] = e;
        float pe = __builtin_amdgcn_exp2f(K1 * e);
        #pragma unroll
        for (int off = 32; off >= 1; off >>= 1) pe += __shfl_xor(pe, off);
        if (lane == 0) Zpart[bq + 4][wv & 3] = pe;
      }
    }
    __syncthreads();  // B3: e_f + Zpart ready

    // ---- softmax redistribution + xt (bf16) ----
    {
      const int b8s = tid >> 7;
      const int nn0 = (tid & 127) * 2;
      f4v zp = *(const f4v*)&Zpart[b8s][0];
      float zi = 1.0f / ((zp.x + zp.y) + (zp.z + zp.w));
      float2 ee = *(const float2*)&e_f[b8s * 256 + nn0];
      float p0 = __builtin_amdgcn_exp2f(K1 * ee.x);
      float p1 = __builtin_amdgcn_exp2f(K1 * ee.y);
      unsigned int packed = (unsigned int)f2bf(p0 * zi * ee.x)
                          | ((unsigned int)f2bf(p1 * zi * ee.y) << 16);
      *(unsigned int*)&xt_b[b8s * 264 + nn0] = packed;
    }
    __syncthreads();  // B4: xt ready

    // ---- xt-part of gates ----
    #pragma unroll
    for (int kt = 0; kt < 8; kt++) {
      s8v aA = *(const s8v*)&xt_b[l15 * 264 + kt * 32 + quad * 8];
      const int r0 = (wv * 16 + l15) * 256;
      s8v b0 = *(const s8v*)&Wih_b[(size_t)(     0 + r0) + kt * 32 + quad * 8];
      s8v b1 = *(const s8v*)&Wih_b[(size_t)( 65536 + r0) + kt * 32 + quad * 8];
      s8v b2 = *(const s8v*)&Wih_b[(size_t)(131072 + r0) + kt * 32 + quad * 8];
      s8v b3 = *(const s8v*)&Wih_b[(size_t)(196608 + r0) + kt * 32 + quad * 8];
      ga0 = MFMA16(aA, b0, ga0); ga1 = MFMA16(aA, b1, ga1);
      ga2 = MFMA16(aA, b2, ga2); ga3 = MFMA16(aA, b3, ga3);
    }

    // ---- pointwise LSTM straight from accumulators (lanes 0..31) ----
    if (lane < 32) {
      const int jj = wv * 16 + l15;
      #pragma unroll
      for (int r = 0; r < 4; r++) {
        const int m = quad * 4 + r;
        float iG = ga0[r] + bsum[jj];
        float fG = ga1[r] + bsum[256 + jj];
        float gG = ga2[r] + bsum[512 + jj];
        float oG = ga3[r] + bsum[768 + jj];
        float si = __builtin_amdgcn_rcpf(1.0f + __builtin_amdgcn_exp2f(-K1 * iG));
        float sf = __builtin_amdgcn_rcpf(1.0f + __builtin_amdgcn_exp2f(-K1 * fG));
        float so = __builtin_amdgcn_rcpf(1.0f + __builtin_amdgcn_exp2f(-K1 * oG));
        float tg_ = 1.0f - 2.0f * __builtin_amdgcn_rcpf(1.0f + __builtin_amdgcn_exp2f(K2 * gG));
        float cn = sf * c_f[m * 256 + jj] + si * tg_;
        float th = 1.0f - 2.0f * __builtin_amdgcn_rcpf(1.0f + __builtin_amdgcn_exp2f(K2 * cn));
        float hn = so * th;
        c_f[m * 256 + jj] = cn;
        c_b[m * 264 + jj] = f2bf(cn);
        h_b[m * 264 + jj] = f2bf(hn);
        h_hist[(m * 256 + jj) * 20 + (s & 15)] = f2bf(hn);
      }
    }

    // ---- full-line coalesced output dump every 16 steps (plain stores:
    //      L2 write-back merges the 4x16B into whole 64B lines, no RMW) ----
    if ((s & 15) == 15) {
      __syncthreads();
      #pragma unroll
      for (int p = 0; p < 2; p++) {
        int rid = p * 1024 + tid;
        int mB = rid >> 8, j = rid & 255;
        const us4* hp = (const us4*)&h_hist[rid * 20];
        float* dst = &out[(((size_t)blk * 8 + mB) * 256 + j) * 128 + (s - 15)];
        #pragma unroll
        for (int c = 0; c < 4; c++) {
          us4 u = hp[c];
          f4v o = { bfu(u.x), bfu(u.y), bfu(u.z), bfu(u.w) };
          *(f4v*)(dst + c * 4) = o;
        }
      }
    }
  }
}

extern "C" void kernel_launch(void* const* d_in, const int* in_sizes, int n_in,
                              void* d_out, int out_size, void* d_ws, size_t ws_size,
                              hipStream_t stream) {
  const float* x   = (const float*)d_in[0];
  const float* We  = (const float*)d_in[1];
  const float* Ue  = (const float*)d_in[2];
  const float* Ve  = (const float*)d_in[3];
  const float* Wih = (const float*)d_in[4];
  const float* Whh = (const float*)d_in[5];
  const float* bih = (const float*)d_in[6];
  const float* bhh = (const float*)d_in[7];
  float* out = (float*)d_out;

  char* p = (char*)d_ws;
  unsigned char*  UxK8  = (unsigned char*)p;  p += (size_t)67108864; // 2048*256*128 fp8
  unsigned short* Wih_b = (unsigned short*)p; p += 524288;
  unsigned short* Whh_b = (unsigned short*)p; p += 524288;
  unsigned short* We_b  = (unsigned short*)p; p += 131072;
  unsigned short* Ue_b  = (unsigned short*)p; p += 32768;
  float* bsum = (float*)p;

  prep_kernel<<<512, 256, 0, stream>>>(We, Ue, Wih, Whh, bih, bhh,
                                       Wih_b, Whh_b, We_b, Ue_b, bsum);
  ux_kernel<<<8192, 256, 0, stream>>>(x, Ue_b, UxK8);
  rnn_kernel<<<256, 1024, 0, stream>>>(UxK8, We_b, Wih_b, Whh_b, bsum, Ve, out);
}

// Round 6
// 9887.534 us; speedup vs baseline: 1.6574x; 1.0672x over previous
//
#include <hip/hip_runtime.h>
#include <stdint.h>

typedef short  s8v  __attribute__((ext_vector_type(8)));
typedef float  f4v  __attribute__((ext_vector_type(4)));
typedef float  f2v  __attribute__((ext_vector_type(2)));
typedef int    i4v  __attribute__((ext_vector_type(4)));
typedef unsigned short us4 __attribute__((ext_vector_type(4)));

#define MFMA16(a,b,c) __builtin_amdgcn_mfma_f32_16x16x32_bf16(a,b,c,0,0,0)

#define K1 1.44269504088896340f   /* log2(e)   */
#define K2 2.88539008177792681f   /* 2*log2(e) */

__device__ __forceinline__ unsigned short f2bf(float f) {
  union { float f; uint32_t u; } v; v.f = f;
  return (unsigned short)((v.u + 0x7FFFu + ((v.u >> 16) & 1u)) >> 16);
}
__device__ __forceinline__ float bflo(uint32_t dw) {
  union { uint32_t u; float f; } v; v.u = dw << 16; return v.f;
}
__device__ __forceinline__ float bfhi(uint32_t dw) {
  union { uint32_t u; float f; } v; v.u = dw & 0xFFFF0000u; return v.f;
}
__device__ __forceinline__ float bfu(unsigned short u) {
  union { uint32_t u; float f; } v; v.u = ((uint32_t)u) << 16; return v.f;
}

// ---- AGPR stash (working since round 5: FETCH −7.4 GB) ----
__device__ __forceinline__ void agpr_w(int& a, int v) {
  asm volatile("v_accvgpr_write_b32 %0, %1" : "=a"(a) : "v"(v));
}
__device__ __forceinline__ int agpr_r(int& a) {
  int v;
  asm volatile("v_accvgpr_read_b32 %0, %1" : "=v"(v) : "a"(a));
  return v;
}
#define DECL_STASH(nm) int nm##_0, nm##_1, nm##_2, nm##_3
#define STASH(nm, vec) do { i4v _t = (vec); \
  agpr_w(nm##_0, _t[0]); agpr_w(nm##_1, _t[1]); \
  agpr_w(nm##_2, _t[2]); agpr_w(nm##_3, _t[3]); } while (0)
#define LOAD4(nm) __extension__({ i4v _c; \
  _c[0] = agpr_r(nm##_0); _c[1] = agpr_r(nm##_1); \
  _c[2] = agpr_r(nm##_2); _c[3] = agpr_r(nm##_3); _c; })

// one 16-t chunk of the attention sum; tg must be a compile-time constant.
__device__ __forceinline__ void att_accum(i4v cur, const f4v* __restrict__ wvf, int tg,
                                          float& a0, float& a1, float& a2, float& a3) {
  #pragma unroll
  for (int q = 0; q < 4; q++) {
    uint32_t dw = (uint32_t)cur[q];
    f2v lo = __builtin_amdgcn_cvt_pk_f32_fp8(dw, 0);
    f2v hi = __builtin_amdgcn_cvt_pk_f32_fp8(dw, 1);
    const int t = tg * 16 + q * 4;
    f4v w01 = wvf[(t >> 1)];       // (whs_t, -2V_t, whs_t+1, -2V_t+1)
    f4v w23 = wvf[(t >> 1) + 1];
    float x0 = lo.x + w01.x;
    a0 = fmaf(w01.y, __builtin_amdgcn_rcpf(__builtin_amdgcn_exp2f(x0) + 1.0f), a0);
    float x1 = lo.y + w01.z;
    a1 = fmaf(w01.w, __builtin_amdgcn_rcpf(__builtin_amdgcn_exp2f(x1) + 1.0f), a1);
    float x2 = hi.x + w23.x;
    a2 = fmaf(w23.y, __builtin_amdgcn_rcpf(__builtin_amdgcn_exp2f(x2) + 1.0f), a2);
    float x3 = hi.y + w23.z;
    a3 = fmaf(w23.w, __builtin_amdgcn_rcpf(__builtin_amdgcn_exp2f(x3) + 1.0f), a3);
  }
}

// one full 8-kt gate GEMM accumulation against LDS A-tile a_lds and weight W.
__device__ __forceinline__ void gate_gemm(
    const unsigned short* __restrict__ a_lds,
    const unsigned short* __restrict__ W,
    int l15, int quad, int wv,
    f4v& ga0, f4v& ga1, f4v& ga2, f4v& ga3)
{
  #pragma unroll
  for (int kt = 0; kt < 8; kt++) {
    s8v aA = *(const s8v*)&a_lds[l15 * 264 + kt * 32 + quad * 8];
    const int r0 = (wv * 16 + l15) * 256;
    s8v b0 = *(const s8v*)&W[(size_t)(     0 + r0) + kt * 32 + quad * 8];
    s8v b1 = *(const s8v*)&W[(size_t)( 65536 + r0) + kt * 32 + quad * 8];
    s8v b2 = *(const s8v*)&W[(size_t)(131072 + r0) + kt * 32 + quad * 8];
    s8v b3 = *(const s8v*)&W[(size_t)(196608 + r0) + kt * 32 + quad * 8];
    ga0 = MFMA16(aA, b0, ga0); ga1 = MFMA16(aA, b1, ga1);
    ga2 = MFMA16(aA, b2, ga2); ga3 = MFMA16(aA, b3, ga3);
  }
}

// ---------------- prep: convert weights to bf16, sum biases ----------------
__global__ __launch_bounds__(256) void prep_kernel(
    const float* __restrict__ We, const float* __restrict__ Ue,
    const float* __restrict__ Wih, const float* __restrict__ Whh,
    const float* __restrict__ bih, const float* __restrict__ bhh,
    unsigned short* __restrict__ Wih_b, unsigned short* __restrict__ Whh_b,
    unsigned short* __restrict__ We_b, unsigned short* __restrict__ Ue_b,
    float* __restrict__ bsum)
{
  int i0 = blockIdx.x * 256 + threadIdx.x;
  int stride = gridDim.x * 256;
  for (int i = i0; i < 262144; i += stride) Wih_b[i] = f2bf(Wih[i]);
  for (int i = i0; i < 262144; i += stride) Whh_b[i] = f2bf(Whh[i]);
  for (int i = i0; i < 65536;  i += stride) We_b[i]  = f2bf(We[i]);
  for (int i = i0; i < 16384;  i += stride) Ue_b[i]  = f2bf(Ue[i]);
  for (int i = i0; i < 1024;   i += stride) bsum[i]  = bih[i] + bhh[i];
}

// ---- Ux GEMM: UxK8[b][tg][n][16] = fp8(K2 * sum_t x[b][t][n]*U_e[s][t]) ----
__global__ __launch_bounds__(256) void ux_kernel(
    const float* __restrict__ x, const unsigned short* __restrict__ Ue_b,
    unsigned char* __restrict__ UxK8)
{
  __shared__ unsigned short xT[64 * 136];
  __shared__ unsigned short oT[64 * 136];
  const int tid = threadIdx.x;
  const int b   = blockIdx.x >> 2;
  const int n0  = (blockIdx.x & 3) * 64;

  {
    const int nl = tid & 63, tp = tid >> 6;
    for (int i = 0; i < 32; i++) {
      int t = tp + i * 4;
      xT[nl * 136 + t] = f2bf(x[((size_t)b * 128 + t) * 256 + n0 + nl]);
    }
  }
  __syncthreads();
  {
    const int w = tid >> 6, lane = tid & 63;
    const int l15 = lane & 15, quad = lane >> 4;
    for (int tt = 0; tt < 8; tt++) {
      f4v acc = {0.f, 0.f, 0.f, 0.f};
      #pragma unroll
      for (int kt = 0; kt < 4; kt++) {
        s8v a  = *(const s8v*)&xT[(w * 16 + l15) * 136 + kt * 32 + quad * 8];
        s8v bb = *(const s8v*)&Ue_b[(tt * 16 + l15) * 128 + kt * 32 + quad * 8];
        acc = MFMA16(a, bb, acc);
      }
      #pragma unroll
      for (int r = 0; r < 4; r++)
        oT[(w * 16 + quad * 4 + r) * 136 + tt * 16 + l15] = f2bf(acc[r] * K2);
    }
  }
  __syncthreads();
  {
    for (int p = 0; p < 2; p++) {
      int row = (tid >> 3) + p * 32;
      int tg  = tid & 7;
      const unsigned int* sp = (const unsigned int*)&oT[row * 136 + tg * 16];
      i4v outv;
      #pragma unroll
      for (int j = 0; j < 4; j++) {
        unsigned int d0 = sp[2 * j], d1 = sp[2 * j + 1];
        int w = __builtin_amdgcn_cvt_pk_fp8_f32(bflo(d0), bfhi(d0), 0, 0);
        w     = __builtin_amdgcn_cvt_pk_fp8_f32(bflo(d1), bfhi(d1), w, 1);
        outv[j] = w;
      }
      *(i4v*)&UxK8[(((size_t)b * 8 + tg) * 256 + n0 + row) * 16] = outv;
    }
  }
}

// ---------------- persistent recurrence: 256 blocks x 1024 thr, 8 batch/blk --
__global__ __launch_bounds__(1024, 4) void rnn_kernel(
    const unsigned char* __restrict__ UxK8,
    const unsigned short* __restrict__ We_b,
    const unsigned short* __restrict__ Wih_b,
    const unsigned short* __restrict__ Whh_b,
    const float* __restrict__ bsum_g,
    const float* __restrict__ Ve,
    float* __restrict__ out)
{
  __shared__ unsigned short h_hist[2048 * 20];
  __shared__ unsigned short xt_b[16 * 264];
  __shared__ unsigned short h_b [16 * 264];
  __shared__ unsigned short c_b [16 * 264];
  __shared__ float  c_f[8 * 256];
  __shared__ float  e_f[8 * 256];
  __shared__ float  wv_lds[8 * 128 * 2];
  __shared__ float  bsum[1024];
  __shared__ float  Zpart[8][4];

  const int tid  = threadIdx.x;
  const int wv   = tid >> 6;
  const int lane = tid & 63;
  const int l15  = lane & 15;
  const int quad = lane >> 4;
  const int blk  = blockIdx.x;

  for (int i = tid; i < 16 * 264; i += 1024) { xt_b[i] = 0; h_b[i] = 0; c_b[i] = 0; }
  for (int i = tid; i < 2048; i += 1024) c_f[i] = 0.f;
  bsum[tid] = bsum_g[tid];
  {
    int b8 = tid >> 7, t = tid & 127;
    wv_lds[(b8 * 128 + t) * 2 + 1] = -2.0f * Ve[t];
    wv_lds[(b8 * 128 + t) * 2 + 0] = 0.f;
  }
  float Vs = 0.f;
  for (int t = 0; t < 128; t++) Vs += Ve[t];
  __syncthreads();

  const int an = tid & 255;
  const int bq = tid >> 8;

  const i4v* ub = (const i4v*)UxK8;
  const size_t ux_base0 = ((size_t)(blk * 8 + bq)    ) * 2048 + an;
  const size_t ux_base1 = ((size_t)(blk * 8 + bq + 4)) * 2048 + an;

  DECL_STASH(u0); DECL_STASH(u1); DECL_STASH(u2); DECL_STASH(u3);
  DECL_STASH(u4); DECL_STASH(u5); DECL_STASH(u6); DECL_STASH(u7);
  DECL_STASH(w0); DECL_STASH(w1); DECL_STASH(w2); DECL_STASH(w3);
  DECL_STASH(w4); DECL_STASH(w5); DECL_STASH(w6); DECL_STASH(w7);
  STASH(u0, ub[ux_base0]);
  STASH(u1, ub[ux_base0 + 256]);
  STASH(u2, ub[ux_base0 + 512]);
  STASH(u3, ub[ux_base0 + 768]);
  STASH(u4, ub[ux_base0 + 1024]);
  STASH(u5, ub[ux_base0 + 1280]);
  STASH(u6, ub[ux_base0 + 1536]);
  STASH(u7, ub[ux_base0 + 1792]);
  STASH(w0, ub[ux_base1]);
  STASH(w1, ub[ux_base1 + 256]);
  STASH(w2, ub[ux_base1 + 512]);
  STASH(w3, ub[ux_base1 + 768]);
  STASH(w4, ub[ux_base1 + 1024]);
  STASH(w5, ub[ux_base1 + 1280]);
  STASH(w6, ub[ux_base1 + 1536]);
  STASH(w7, ub[ux_base1 + 1792]);

  f4v ga0, ga1, ga2, ga3;

  for (int s = 0; s < 128; s++) {
    __syncthreads();   // B1: h_b/c_b stable from previous step

    ga0 = (f4v){0.f,0.f,0.f,0.f}; ga1 = ga0; ga2 = ga0; ga3 = ga0;

    // ---- wave-role split (round-6 change): waves 0-7 compute whs while
    // waves 8-15 run their h-gate GEMM (inputs h_b + Whh are ready at B1).
    // After B2, waves 8-15 enter the attention VALU immediately while waves
    // 0-7 issue their h-gate loads — the SIMD always holds both a
    // load-issuing and a VALU-issuing wave, hiding weight-fetch latency
    // under attention compute and removing the whs phase from the other
    // 8 waves' critical path.
    if (wv < 8) {
      f4v acc = {0.f, 0.f, 0.f, 0.f};
      #pragma unroll
      for (int kt = 0; kt < 8; kt++) {
        s8v a  = *(const s8v*)&h_b[l15 * 264 + kt * 32 + quad * 8];
        s8v bb = *(const s8v*)&We_b[(wv * 16 + l15) * 512 + kt * 32 + quad * 8];
        acc = MFMA16(a, bb, acc);
      }
      #pragma unroll
      for (int kt = 0; kt < 8; kt++) {
        s8v a  = *(const s8v*)&c_b[l15 * 264 + kt * 32 + quad * 8];
        s8v bb = *(const s8v*)&We_b[(wv * 16 + l15) * 512 + 256 + kt * 32 + quad * 8];
        acc = MFMA16(a, bb, acc);
      }
      if (lane < 32) {
        #pragma unroll
        for (int r = 0; r < 4; r++)
          wv_lds[((quad * 4 + r) * 128 + wv * 16 + l15) * 2] = K2 * acc[r];
      }
    } else {
      gate_gemm(h_b, Whh_b, l15, quad, wv, ga0, ga1, ga2, ga3);
    }
    __syncthreads();   // B2: whsK ready

    if (wv < 8) {
      gate_gemm(h_b, Whh_b, l15, quad, wv, ga0, ga1, ga2, ga3);
    }

    // ---- attention: e[b][n] = Vs + sum_t (-2 V[t]) / (exp2(UxK+whsK)+1) ----
    {
      const f4v* wvf0 = (const f4v*)&wv_lds[bq * 256];
      float a0 = 0.f, a1 = 0.f, a2 = 0.f, a3 = 0.f;
      att_accum(LOAD4(u0), wvf0, 0, a0, a1, a2, a3);
      att_accum(LOAD4(u1), wvf0, 1, a0, a1, a2, a3);
      att_accum(LOAD4(u2), wvf0, 2, a0, a1, a2, a3);
      att_accum(LOAD4(u3), wvf0, 3, a0, a1, a2, a3);
      att_accum(LOAD4(u4), wvf0, 4, a0, a1, a2, a3);
      att_accum(LOAD4(u5), wvf0, 5, a0, a1, a2, a3);
      att_accum(LOAD4(u6), wvf0, 6, a0, a1, a2, a3);
      att_accum(LOAD4(u7), wvf0, 7, a0, a1, a2, a3);
      {
        float e = Vs + ((a0 + a1) + (a2 + a3));
        e_f[bq * 256 + an] = e;
        float pe = __builtin_amdgcn_exp2f(K1 * e);
        #pragma unroll
        for (int off = 32; off >= 1; off >>= 1) pe += __shfl_xor(pe, off);
        if (lane == 0) Zpart[bq][wv & 3] = pe;
      }

      const f4v* wvf1 = (const f4v*)&wv_lds[(bq + 4) * 256];
      a0 = 0.f; a1 = 0.f; a2 = 0.f; a3 = 0.f;
      att_accum(LOAD4(w0), wvf1, 0, a0, a1, a2, a3);
      att_accum(LOAD4(w1), wvf1, 1, a0, a1, a2, a3);
      att_accum(LOAD4(w2), wvf1, 2, a0, a1, a2, a3);
      att_accum(LOAD4(w3), wvf1, 3, a0, a1, a2, a3);
      att_accum(LOAD4(w4), wvf1, 4, a0, a1, a2, a3);
      att_accum(LOAD4(w5), wvf1, 5, a0, a1, a2, a3);
      att_accum(LOAD4(w6), wvf1, 6, a0, a1, a2, a3);
      att_accum(LOAD4(w7), wvf1, 7, a0, a1, a2, a3);
      {
        float e = Vs + ((a0 + a1) + (a2 + a3));
        e_f[(bq + 4) * 256 + an] = e;
        float pe = __builtin_amdgcn_exp2f(K1 * e);
        #pragma unroll
        for (int off = 32; off >= 1; off >>= 1) pe += __shfl_xor(pe, off);
        if (lane == 0) Zpart[bq + 4][wv & 3] = pe;
      }
    }
    __syncthreads();  // B3: e_f + Zpart ready

    // ---- softmax redistribution + xt (bf16) ----
    {
      const int b8s = tid >> 7;
      const int nn0 = (tid & 127) * 2;
      f4v zp = *(const f4v*)&Zpart[b8s][0];
      float zi = 1.0f / ((zp.x + zp.y) + (zp.z + zp.w));
      float2 ee = *(const float2*)&e_f[b8s * 256 + nn0];
      float p0 = __builtin_amdgcn_exp2f(K1 * ee.x);
      float p1 = __builtin_amdgcn_exp2f(K1 * ee.y);
      unsigned int packed = (unsigned int)f2bf(p0 * zi * ee.x)
                          | ((unsigned int)f2bf(p1 * zi * ee.y) << 16);
      *(unsigned int*)&xt_b[b8s * 264 + nn0] = packed;
    }
    __syncthreads();  // B4: xt ready

    // ---- xt-part of gates (all 16 waves) ----
    gate_gemm(xt_b, Wih_b, l15, quad, wv, ga0, ga1, ga2, ga3);

    // ---- pointwise LSTM straight from accumulators (lanes 0..31) ----
    if (lane < 32) {
      const int jj = wv * 16 + l15;
      #pragma unroll
      for (int r = 0; r < 4; r++) {
        const int m = quad * 4 + r;
        float iG = ga0[r] + bsum[jj];
        float fG = ga1[r] + bsum[256 + jj];
        float gG = ga2[r] + bsum[512 + jj];
        float oG = ga3[r] + bsum[768 + jj];
        float si = __builtin_amdgcn_rcpf(1.0f + __builtin_amdgcn_exp2f(-K1 * iG));
        float sf = __builtin_amdgcn_rcpf(1.0f + __builtin_amdgcn_exp2f(-K1 * fG));
        float so = __builtin_amdgcn_rcpf(1.0f + __builtin_amdgcn_exp2f(-K1 * oG));
        float tg_ = 1.0f - 2.0f * __builtin_amdgcn_rcpf(1.0f + __builtin_amdgcn_exp2f(K2 * gG));
        float cn = sf * c_f[m * 256 + jj] + si * tg_;
        float th = 1.0f - 2.0f * __builtin_amdgcn_rcpf(1.0f + __builtin_amdgcn_exp2f(K2 * cn));
        float hn = so * th;
        c_f[m * 256 + jj] = cn;
        c_b[m * 264 + jj] = f2bf(cn);
        h_b[m * 264 + jj] = f2bf(hn);
        h_hist[(m * 256 + jj) * 20 + (s & 15)] = f2bf(hn);
      }
    }

    // ---- full-line coalesced output dump every 16 steps ----
    if ((s & 15) == 15) {
      __syncthreads();
      #pragma unroll
      for (int p = 0; p < 2; p++) {
        int rid = p * 1024 + tid;
        int mB = rid >> 8, j = rid & 255;
        const us4* hp = (const us4*)&h_hist[rid * 20];
        float* dst = &out[(((size_t)blk * 8 + mB) * 256 + j) * 128 + (s - 15)];
        #pragma unroll
        for (int c = 0; c < 4; c++) {
          us4 u = hp[c];
          f4v o = { bfu(u.x), bfu(u.y), bfu(u.z), bfu(u.w) };
          *(f4v*)(dst + c * 4) = o;
        }
      }
    }
  }
}

extern "C" void kernel_launch(void* const* d_in, const int* in_sizes, int n_in,
                              void* d_out, int out_size, void* d_ws, size_t ws_size,
                              hipStream_t stream) {
  const float* x   = (const float*)d_in[0];
  const float* We  = (const float*)d_in[1];
  const float* Ue  = (const float*)d_in[2];
  const float* Ve  = (const float*)d_in[3];
  const float* Wih = (const float*)d_in[4];
  const float* Whh = (const float*)d_in[5];
  const float* bih = (const float*)d_in[6];
  const float* bhh = (const float*)d_in[7];
  float* out = (float*)d_out;

  char* p = (char*)d_ws;
  unsigned char*  UxK8  = (unsigned char*)p;  p += (size_t)67108864; // 2048*256*128 fp8
  unsigned short* Wih_b = (unsigned short*)p; p += 524288;
  unsigned short* Whh_b = (unsigned short*)p; p += 524288;
  unsigned short* We_b  = (unsigned short*)p; p += 131072;
  unsigned short* Ue_b  = (unsigned short*)p; p += 32768;
  float* bsum = (float*)p;

  prep_kernel<<<512, 256, 0, stream>>>(We, Ue, Wih, Whh, bih, bhh,
                                       Wih_b, Whh_b, We_b, Ue_b, bsum);
  ux_kernel<<<8192, 256, 0, stream>>>(x, Ue_b, UxK8);
  rnn_kernel<<<256, 1024, 0, stream>>>(UxK8, We_b, Wih_b, Whh_b, bsum, Ve, out);
}